// Round 2
// baseline (5025.947 us; speedup 1.0000x reference)
//
#include <hip/hip_runtime.h>
#include <hip/hip_bf16.h>
#include <math.h>

// Problem constants (fixed by the reference)
#define NN 1024
#define HH 64
#define KK 2
#define TT 12
#define BB 8
#define INDIM 2
#define LL 2
#define NNZE 16384
#define MM 5

static constexpr size_t BNH = (size_t)BB * NN * HH; // 524288

// ---------------- small utility kernels ----------------
__global__ void zero_int_kernel(int* p, int n) {
  int i = blockIdx.x * blockDim.x + threadIdx.x;
  if (i < n) p[i] = 0;
}

__global__ void copy_kernel(const float* __restrict__ src, float* __restrict__ dst, int n) {
  int i = blockIdx.x * blockDim.x + threadIdx.x;
  if (i < n) dst[i] = src[i];
}

// ---------------- CSR build (per support) ----------------
__global__ void csr_count_kernel(const int* __restrict__ rows, int* __restrict__ counts) {
  int i = blockIdx.x * blockDim.x + threadIdx.x;
  if (i < 2 * NNZE) {
    int s = i / NNZE;
    atomicAdd(&counts[s * NN + rows[i]], 1);
  }
}

// one block per support; 1024 threads; Hillis-Steele inclusive scan in LDS
__global__ void csr_scan_kernel(const int* __restrict__ counts, int* __restrict__ row_start,
                                int* __restrict__ cursor) {
  __shared__ int bufA[NN];
  __shared__ int bufB[NN];
  int s = blockIdx.x;
  int t = threadIdx.x;
  bufA[t] = counts[s * NN + t];
  __syncthreads();
  int* src = bufA;
  int* dst = bufB;
  for (int off = 1; off < NN; off <<= 1) {
    dst[t] = src[t] + (t >= off ? src[t - off] : 0);
    __syncthreads();
    int* tmp = src; src = dst; dst = tmp;
  }
  // src now holds inclusive scan
  row_start[s * (NN + 1) + t + 1] = src[t];
  cursor[s * NN + t] = (t == 0) ? 0 : src[t - 1];
  if (t == 0) row_start[s * (NN + 1)] = 0;
}

__global__ void csr_scatter_kernel(const int* __restrict__ rows, const int* __restrict__ colsIn,
                                   const float* __restrict__ valsIn, int* __restrict__ cursor,
                                   int* __restrict__ colsOut, float* __restrict__ valsOut) {
  int i = blockIdx.x * blockDim.x + threadIdx.x;
  if (i < 2 * NNZE) {
    int s = i / NNZE;
    int r = rows[i];
    int pos = atomicAdd(&cursor[s * NN + r], 1);   // 0-based within support s
    colsOut[s * NNZE + pos] = colsIn[i];
    valsOut[s * NNZE + pos] = valsIn[i];
  }
}

// ---------------- weight permutation ----------------
// Wp[m*F + f][j] = W[f*M + m][j]  (so GEMM K-order can be (m outer, f inner))
__global__ void permw_kernel(const float* __restrict__ W, float* __restrict__ Wp, int F, int J) {
  int total = MM * F * J;
  for (int idx = blockIdx.x * blockDim.x + threadIdx.x; idx < total;
       idx += gridDim.x * blockDim.x) {
    int j = idx % J;
    int rp = idx / J;
    int m = rp / F;
    int f = rp - m * F;
    Wp[idx] = W[(size_t)(f * MM + m) * J + j];
  }
}

// ---------------- fused x0-build + first diffusion hop ----------------
// x0 (conceptual) layout [n][b][f], f = concat(xi features, state[*r if MODE]).
// One block per (row r, support s). Gathers x0[col] entries directly from the
// source arrays (xi, state, gates) -> computes x1_s row r = sum v * x0[col].
// Writes mats[1+2s] row r; block s==0 also materializes mats[0] row r.
template <int MODE>
__global__ __launch_bounds__(256) void spmm1_fused_kernel(
    const int* __restrict__ row_start, const int* __restrict__ cols,
    const float* __restrict__ vals, const float* __restrict__ xi,
    const float* __restrict__ state, const float* __restrict__ gates,
    float* __restrict__ mats, int Fin) {
  const int F = Fin + HH;
  const int C = BB * F;
  const size_t NC = (size_t)NN * C;
  const int r = blockIdx.x;
  const int s = blockIdx.y;
  const int tid = threadIdx.x;

  // per-slot source mapping (c fixed per thread across the gather loop)
  bool active[4]; bool isX[4];
  size_t baseM[4]; size_t baseG[4];
#pragma unroll
  for (int i = 0; i < 4; ++i) {
    int c = tid + i * 256;
    active[i] = (c < C);
    int b = c / F;            // runtime div, 4x per thread only
    int f = c - b * F;
    if (f < Fin) {
      isX[i] = true;
      baseM[i] = (size_t)b * NN * Fin + f;            // + col*Fin
      baseG[i] = 0;
    } else {
      isX[i] = false;
      int h = f - Fin;
      baseM[i] = (size_t)b * NN * HH + h;             // + col*HH
      baseG[i] = (size_t)b * NN * (2 * HH) + h;       // + col*2H (r gate)
    }
  }

  const int* rs = row_start + s * (NN + 1);
  const int* cs = cols + s * NNZE;
  const float* vs = vals + s * NNZE;
  const int start = rs[r], end = rs[r + 1];

  float acc[4] = {0.f, 0.f, 0.f, 0.f};
  for (int e = start; e < end; ++e) {
    int col = cs[e];
    float v = vs[e];
#pragma unroll
    for (int i = 0; i < 4; ++i) {
      if (!active[i]) continue;
      float x;
      if (isX[i]) {
        x = xi[baseM[i] + (size_t)col * Fin];
      } else {
        x = state[baseM[i] + (size_t)col * HH];
        if (MODE) x *= gates[baseG[i] + (size_t)col * (2 * HH)];
      }
      acc[i] += v * x;
    }
  }

  float* x1row = mats + (size_t)(1 + 2 * s) * NC + (size_t)r * C;
#pragma unroll
  for (int i = 0; i < 4; ++i)
    if (active[i]) x1row[tid + i * 256] = acc[i];

  if (s == 0) {  // materialize x0 row r for GEMM + spmm2 consumers
    float* x0row = mats + (size_t)r * C;
#pragma unroll
    for (int i = 0; i < 4; ++i) {
      if (!active[i]) continue;
      float x;
      if (isX[i]) {
        x = xi[baseM[i] + (size_t)r * Fin];
      } else {
        x = state[baseM[i] + (size_t)r * HH];
        if (MODE) x *= gates[baseG[i] + (size_t)r * (2 * HH)];
      }
      x0row[tid + i * 256] = x;
    }
  }
}

// ---------------- second diffusion hop: x2 = 2*A*x1 - x0 ----------------
__global__ __launch_bounds__(256) void spmm2_kernel(
    const int* __restrict__ row_start, const int* __restrict__ cols,
    const float* __restrict__ vals, float* mats, int C) {
  int r = blockIdx.x;
  int s = blockIdx.y;
  size_t NC = (size_t)NN * C;
  const float* xin = mats + (size_t)(1 + 2 * s) * NC;
  const float* x0 = mats;
  float* xout = mats + (size_t)(2 + 2 * s) * NC;

  const int* rs = row_start + s * (NN + 1);
  const int* cs = cols + s * NNZE;
  const float* vs = vals + s * NNZE;
  int start = rs[r], end = rs[r + 1];
  int tid = threadIdx.x;

  float acc[4] = {0.f, 0.f, 0.f, 0.f};
  for (int e = start; e < end; ++e) {
    int col = cs[e];
    float v = vs[e];
    const float* xr = xin + (size_t)col * C;
#pragma unroll
    for (int i = 0; i < 4; ++i) {
      int c = tid + i * 256;
      if (c < C) acc[i] += v * xr[c];
    }
  }
  float* orow = xout + (size_t)r * C;
  const float* pp = x0 + (size_t)r * C;
#pragma unroll
  for (int i = 0; i < 4; ++i) {
    int c = tid + i * 256;
    if (c < C) orow[c] = 2.f * acc[i] - pp[c];
  }
}

// ---------------- tiled fp32 GEMM with fused epilogue ----------------
// out[bn, j] = sum_{m,f} mats[m][n][b][f] * Wp[m*F+f][j] + bias[j]
// MODE 0: gatesOut[bn][j] = sigmoid(out)   (J = 128)
// MODE 1: c = tanh(out); u = gatesIn[bn][H+j]; ns = u*s + (1-u)*c;
//         state[b,n,j] = ns; outT[b,n,j] = ns   (J = 64)
// Tile 32x32, 2x2 per thread, 256 threads -> high block count for occupancy.
template <int MODE>
__global__ __launch_bounds__(256) void gemm_kernel(
    const float* __restrict__ mats, const float* __restrict__ Wp, const float* __restrict__ bias,
    float* __restrict__ gatesOut, const float* __restrict__ gatesIn, float* __restrict__ state,
    float* __restrict__ outT, int F, int J) {
  constexpr int BMt = 32, BNt = 32, KT = 16;
  __shared__ float As[KT][BMt + 2];  // +2 keeps float2 alignment, spreads banks
  __shared__ float Ws[KT][BNt];
  const int tid = threadIdx.x;
  const int tx = tid & 15;          // 16 col positions * 2
  const int ty = tid >> 4;          // 16 row positions * 2
  const int bn0 = blockIdx.x * BMt;
  const int jb0 = blockIdx.y * BNt;
  const int C = BB * F;
  float acc[2][2] = {};

  for (int m = 0; m < MM; ++m) {
    const float* matm = mats + (size_t)m * NN * C;
    for (int f0 = 0; f0 < F; f0 += KT) {
      // A tile [BMt x KT] -> As[fi][row]   (512 elems = 256 thr * 2)
#pragma unroll
      for (int i = 0; i < 2; ++i) {
        int idx = tid + i * 256;
        int row = idx >> 4;
        int fi = idx & 15;
        int bn = bn0 + row;
        int n = bn & (NN - 1);
        int b = bn >> 10;
        int fg = f0 + fi;
        As[fi][row] = (fg < F) ? matm[(size_t)n * C + b * F + fg] : 0.f;
      }
      // W tile [KT x BNt]   (512 elems)
#pragma unroll
      for (int i = 0; i < 2; ++i) {
        int idx = tid + i * 256;
        int j = idx & (BNt - 1);
        int fi = idx >> 5;
        int fg = f0 + fi;
        Ws[fi][j] = (fg < F) ? Wp[(size_t)(m * F + fg) * J + jb0 + j] : 0.f;
      }
      __syncthreads();
#pragma unroll
      for (int k = 0; k < KT; ++k) {
        float av[2], wv[2];
        *(float2*)av = *(const float2*)&As[k][ty * 2];
        *(float2*)wv = *(const float2*)&Ws[k][tx * 2];
#pragma unroll
        for (int i = 0; i < 2; ++i)
#pragma unroll
          for (int j = 0; j < 2; ++j) acc[i][j] += av[i] * wv[j];
      }
      __syncthreads();
    }
  }

#pragma unroll
  for (int i = 0; i < 2; ++i) {
    int bn = bn0 + ty * 2 + i;
    int n = bn & (NN - 1);
    int b = bn >> 10;
#pragma unroll
    for (int j = 0; j < 2; ++j) {
      int jj = jb0 + tx * 2 + j;
      float v = acc[i][j] + bias[jj];
      if (MODE == 0) {
        v = 1.f / (1.f + expf(-v));
        gatesOut[(size_t)bn * (2 * HH) + jj] = v;
      } else {
        float c = tanhf(v);
        float u = gatesIn[(size_t)bn * (2 * HH) + HH + jj];
        size_t si = (size_t)b * (NN * HH) + (size_t)n * HH + jj;
        float s = state[si];
        float ns = u * s + (1.f - u) * c;
        state[si] = ns;
        outT[si] = ns;
      }
    }
  }
}

// ---------------- host orchestration ----------------
extern "C" void kernel_launch(void* const* d_in, const int* in_sizes, int n_in, void* d_out,
                              int out_size, void* d_ws, size_t ws_size, hipStream_t stream) {
  const float* inputs = (const float*)d_in[0];
  const float* init_h = (const float*)d_in[1];
  const int* sup_rows = (const int*)d_in[2];
  const int* sup_cols = (const int*)d_in[3];
  const float* sup_vals = (const float*)d_in[4];
  const float* Wg[2] = {(const float*)d_in[5], (const float*)d_in[9]};
  const float* bg[2] = {(const float*)d_in[6], (const float*)d_in[10]};
  const float* Wc[2] = {(const float*)d_in[7], (const float*)d_in[11]};
  const float* bc[2] = {(const float*)d_in[8], (const float*)d_in[12]};

  float* out_h = (float*)d_out;                    // [L][B*N*H] final hidden states
  float* out_cur = out_h + (size_t)LL * BNH;       // [T][B*N*H] layer-1 outputs

  // --- carve workspace (256B aligned) ---
  char* p = (char*)d_ws;
  auto alloc = [&](size_t bytes) -> void* {
    void* r = (void*)p;
    p += (bytes + 255) & ~(size_t)255;
    return r;
  };
  int* colsS = (int*)alloc(2 * NNZE * sizeof(int));
  float* valsS = (float*)alloc(2 * NNZE * sizeof(float));
  int* row_start = (int*)alloc(2 * (NN + 1) * sizeof(int));
  int* cursor = (int*)alloc(2 * NN * sizeof(int));
  int* counts = (int*)alloc(2 * NN * sizeof(int));
  float* Wgp[2];
  float* Wcp[2];
  Wgp[0] = (float*)alloc((size_t)MM * 66 * 128 * sizeof(float));
  Wcp[0] = (float*)alloc((size_t)MM * 66 * 64 * sizeof(float));
  Wgp[1] = (float*)alloc((size_t)MM * 128 * 128 * sizeof(float));
  Wcp[1] = (float*)alloc((size_t)MM * 128 * 64 * sizeof(float));
  float* mats = (float*)alloc((size_t)MM * NN * BB * 128 * sizeof(float));   // 21 MB max
  float* gatesBuf = (float*)alloc((size_t)BB * NN * 128 * sizeof(float));    // 4 MB
  float* x01 = (float*)alloc(BNH * sizeof(float));                           // layer0 -> layer1

  // --- CSR build (atomic-free SpMM afterwards) ---
  zero_int_kernel<<<(2 * NN + 255) / 256, 256, 0, stream>>>(counts, 2 * NN);
  csr_count_kernel<<<(2 * NNZE + 255) / 256, 256, 0, stream>>>(sup_rows, counts);
  csr_scan_kernel<<<2, NN, 0, stream>>>(counts, row_start, cursor);
  csr_scatter_kernel<<<(2 * NNZE + 255) / 256, 256, 0, stream>>>(sup_rows, sup_cols, sup_vals,
                                                                 cursor, colsS, valsS);
  // --- permute weights to (m,f) K-order ---
  permw_kernel<<<(MM * 66 * 128 + 255) / 256, 256, 0, stream>>>(Wg[0], Wgp[0], 66, 128);
  permw_kernel<<<(MM * 66 * 64 + 255) / 256, 256, 0, stream>>>(Wc[0], Wcp[0], 66, 64);
  permw_kernel<<<(MM * 128 * 128 + 255) / 256, 256, 0, stream>>>(Wg[1], Wgp[1], 128, 128);
  permw_kernel<<<(MM * 128 * 64 + 255) / 256, 256, 0, stream>>>(Wc[1], Wcp[1], 128, 64);
  // --- init states (live directly in d_out hidden slots) ---
  copy_kernel<<<((int)(LL * BNH) + 255) / 256, 256, 0, stream>>>(init_h, out_h, (int)(LL * BNH));

  for (int t = 0; t < TT; ++t) {
    for (int layer = 0; layer < LL; ++layer) {
      const int Fin = (layer == 0) ? INDIM : HH;
      const int F = Fin + HH;
      const int C = BB * F;
      float* state = out_h + (size_t)layer * BNH;
      const float* xi = (layer == 0) ? inputs + (size_t)t * BB * NN * INDIM : x01;
      float* outT = (layer == 0) ? x01 : out_cur + (size_t)t * BNH;

      // gates: fused x0+hop1, hop2, GEMM+sigmoid
      spmm1_fused_kernel<0><<<dim3(NN, 2), 256, 0, stream>>>(row_start, colsS, valsS, xi, state,
                                                             nullptr, mats, Fin);
      spmm2_kernel<<<dim3(NN, 2), 256, 0, stream>>>(row_start, colsS, valsS, mats, C);
      gemm_kernel<0><<<dim3((BB * NN) / 32, (2 * HH) / 32), 256, 0, stream>>>(
          mats, Wgp[layer], bg[layer], gatesBuf, nullptr, nullptr, nullptr, F, 2 * HH);

      // candidate: fused (r*state) x0+hop1, hop2, GEMM+tanh+GRU update
      spmm1_fused_kernel<1><<<dim3(NN, 2), 256, 0, stream>>>(row_start, colsS, valsS, xi, state,
                                                             gatesBuf, mats, Fin);
      spmm2_kernel<<<dim3(NN, 2), 256, 0, stream>>>(row_start, colsS, valsS, mats, C);
      gemm_kernel<1><<<dim3((BB * NN) / 32, HH / 32), 256, 0, stream>>>(
          mats, Wcp[layer], bc[layer], nullptr, gatesBuf, state, outT, F, HH);
    }
  }
}

// Round 4
// 3802.917 us; speedup vs baseline: 1.3216x; 1.3216x over previous
//
#include <hip/hip_runtime.h>
#include <hip/hip_bf16.h>
#include <math.h>

// Problem constants (fixed by the reference)
#define NN 1024
#define HH 64
#define TT 12
#define BB 8
#define INDIM 2
#define LL 2
#define NNZE 16384
#define MM 5

// Padded per-mat feature dims (K-dim per diffusion matrix), multiple of 32
#define FP0 96    // layer0: F = 66 -> 96 (pad zero)
#define FP1 128   // layer1: F = 128
#define CP0 (BB * FP0)   // 768
#define CP1 (BB * FP1)   // 1024

static constexpr size_t BNH = (size_t)BB * NN * HH;  // 524288

// ---------------- small utility kernels ----------------
__global__ void zero_int_kernel(int* p, int n) {
  int i = blockIdx.x * blockDim.x + threadIdx.x;
  if (i < n) p[i] = 0;
}

__global__ void copy_kernel(const float* __restrict__ src, float* __restrict__ dst, int n) {
  int i = blockIdx.x * blockDim.x + threadIdx.x;
  if (i < n) dst[i] = src[i];
}

// ---------------- CSR build (per support) ----------------
__global__ void csr_count_kernel(const int* __restrict__ rows, int* __restrict__ counts) {
  int i = blockIdx.x * blockDim.x + threadIdx.x;
  if (i < 2 * NNZE) {
    int s = i / NNZE;
    atomicAdd(&counts[s * NN + rows[i]], 1);
  }
}

__global__ void csr_scan_kernel(const int* __restrict__ counts, int* __restrict__ row_start,
                                int* __restrict__ cursor) {
  __shared__ int bufA[NN];
  __shared__ int bufB[NN];
  int s = blockIdx.x;
  int t = threadIdx.x;
  bufA[t] = counts[s * NN + t];
  __syncthreads();
  int* src = bufA;
  int* dst = bufB;
  for (int off = 1; off < NN; off <<= 1) {
    dst[t] = src[t] + (t >= off ? src[t - off] : 0);
    __syncthreads();
    int* tmp = src; src = dst; dst = tmp;
  }
  row_start[s * (NN + 1) + t + 1] = src[t];
  cursor[s * NN + t] = (t == 0) ? 0 : src[t - 1];
  if (t == 0) row_start[s * (NN + 1)] = 0;
}

__global__ void csr_scatter_kernel(const int* __restrict__ rows, const int* __restrict__ colsIn,
                                   const float* __restrict__ valsIn, int* __restrict__ cursor,
                                   int* __restrict__ colsOut, float* __restrict__ valsOut) {
  int i = blockIdx.x * blockDim.x + threadIdx.x;
  if (i < 2 * NNZE) {
    int s = i / NNZE;
    int r = rows[i];
    int pos = atomicAdd(&cursor[s * NN + r], 1);
    colsOut[s * NNZE + pos] = colsIn[i];
    valsOut[s * NNZE + pos] = valsIn[i];
  }
}

// ---------------- weight permutation + K-pad ----------------
// Wp[(m*Fp + f)*J + j] = (f < F) ? W[(f*M + m)*J + j] : 0
__global__ void permw_kernel(const float* __restrict__ W, float* __restrict__ Wp, int F, int Fp,
                             int J) {
  int total = MM * Fp * J;
  for (int idx = blockIdx.x * blockDim.x + threadIdx.x; idx < total;
       idx += gridDim.x * blockDim.x) {
    int j = idx % J;
    int rp = idx / J;
    int m = rp / Fp;
    int f = rp - m * Fp;
    Wp[idx] = (f < (F)) ? W[(size_t)(f * MM + m) * J + j] : 0.f;
  }
}

// ---------------- fused x0-build + hop1, layer1 (Fin=64, Fp=128) ----------------
// x0 row layout [b][f] (f = concat(xi_feat, state)), Cp = 1024. One float4/thread.
template <int MODE>
__global__ __launch_bounds__(256) void spmm1_l1_kernel(
    const int* __restrict__ row_start, const int* __restrict__ cols,
    const float* __restrict__ vals, const float* __restrict__ xi,   // [B][N][64]
    const float* __restrict__ state,                                 // [B][N][64]
    const float* __restrict__ gates,                                 // [B*N][128]
    float* __restrict__ mats) {
  const int r = blockIdx.x, s = blockIdx.y, tid = threadIdx.x;
  const int b = tid >> 5;             // c4 = tid*4; b = c4/128
  const int f = (tid & 31) * 4;       // feature offset within [0,128)
  const bool isX = (f < HH);
  const float* src = isX ? xi : state;
  const size_t srcBase = (size_t)b * NN * HH + (isX ? f : f - HH);      // + col*64
  const size_t gBase = (size_t)b * NN * (2 * HH) + (f - HH);            // + col*128

  const int* rs = row_start + s * (NN + 1);
  const int* cs = cols + s * NNZE;
  const float* vs = vals + s * NNZE;
  const int start = rs[r], end = rs[r + 1];

  float4 acc = {0.f, 0.f, 0.f, 0.f};
  for (int e = start; e < end; ++e) {
    int col = cs[e];
    float v = vs[e];
    float4 x = *(const float4*)(src + srcBase + (size_t)col * HH);
    if (MODE && !isX) {
      float4 g = *(const float4*)(gates + gBase + (size_t)col * (2 * HH));
      x.x *= g.x; x.y *= g.y; x.z *= g.z; x.w *= g.w;
    }
    acc.x += v * x.x; acc.y += v * x.y; acc.z += v * x.z; acc.w += v * x.w;
  }
  *(float4*)(mats + (size_t)(1 + 2 * s) * (NN * CP1) + (size_t)r * CP1 + tid * 4) = acc;

  if (s == 0) {  // materialize x0 row r
    float4 x = *(const float4*)(src + srcBase + (size_t)r * HH);
    if (MODE && !isX) {
      float4 g = *(const float4*)(gates + gBase + (size_t)r * (2 * HH));
      x.x *= g.x; x.y *= g.y; x.z *= g.z; x.w *= g.w;
    }
    *(float4*)(mats + (size_t)r * CP1 + tid * 4) = x;
  }
}

// ---------------- fused x0-build + hop1, layer0 (Fin=2, Fp=96) ----------------
template <int MODE>
__global__ __launch_bounds__(256) void spmm1_l0_kernel(
    const int* __restrict__ row_start, const int* __restrict__ cols,
    const float* __restrict__ vals, const float* __restrict__ xi,   // [B][N][2]
    const float* __restrict__ state,                                 // [B][N][64]
    const float* __restrict__ gates,                                 // [B*N][128]
    float* __restrict__ mats) {
  const int tid = threadIdx.x;
  if (tid >= CP0 / 4) return;  // 192 active threads; no barriers in kernel
  const int r = blockIdx.x, s = blockIdx.y;
  const int c4 = tid * 4;
  const int b = c4 / FP0;
  const int f = c4 - b * FP0;

  // per-element descriptors: kind 0=xi, 1=state, 2=pad
  int kind[4];
  size_t sb[4], gb[4];
#pragma unroll
  for (int q = 0; q < 4; ++q) {
    int fe = f + q;
    if (fe < INDIM) {
      kind[q] = 0;
      sb[q] = (size_t)b * NN * INDIM + fe;
      gb[q] = 0;
    } else if (fe < INDIM + HH) {
      kind[q] = 1;
      int h = fe - INDIM;
      sb[q] = (size_t)b * NN * HH + h;
      gb[q] = (size_t)b * NN * (2 * HH) + h;
    } else {
      kind[q] = 2;
      sb[q] = gb[q] = 0;
    }
  }

  const int* rs = row_start + s * (NN + 1);
  const int* cs = cols + s * NNZE;
  const float* vs = vals + s * NNZE;
  const int start = rs[r], end = rs[r + 1];

  float acc[4] = {0.f, 0.f, 0.f, 0.f};
  for (int e = start; e < end; ++e) {
    int col = cs[e];
    float v = vs[e];
#pragma unroll
    for (int q = 0; q < 4; ++q) {
      float x;
      if (kind[q] == 0) {
        x = xi[sb[q] + (size_t)col * INDIM];
      } else if (kind[q] == 1) {
        x = state[sb[q] + (size_t)col * HH];
        if (MODE) x *= gates[gb[q] + (size_t)col * (2 * HH)];
      } else {
        continue;
      }
      acc[q] += v * x;
    }
  }
  float4 av;
  av.x = acc[0]; av.y = acc[1]; av.z = acc[2]; av.w = acc[3];
  *(float4*)(mats + (size_t)(1 + 2 * s) * (NN * CP0) + (size_t)r * CP0 + c4) = av;

  if (s == 0) {
    float x0v[4];
#pragma unroll
    for (int q = 0; q < 4; ++q) {
      float x = 0.f;
      if (kind[q] == 0) {
        x = xi[sb[q] + (size_t)r * INDIM];
      } else if (kind[q] == 1) {
        x = state[sb[q] + (size_t)r * HH];
        if (MODE) x *= gates[gb[q] + (size_t)r * (2 * HH)];
      }
      x0v[q] = x;
    }
    float4 xv;
    xv.x = x0v[0]; xv.y = x0v[1]; xv.z = x0v[2]; xv.w = x0v[3];
    *(float4*)(mats + (size_t)r * CP0 + c4) = xv;
  }
}

// ---------------- hop2: x2 = 2*A@x1 - x0 ----------------
template <int CPX>
__global__ __launch_bounds__(256) void spmm2_kernel(
    const int* __restrict__ row_start, const int* __restrict__ cols,
    const float* __restrict__ vals, float* __restrict__ mats) {
  const int tid = threadIdx.x;
  if (tid * 4 >= CPX) return;
  const int r = blockIdx.x, s = blockIdx.y;
  const size_t NC = (size_t)NN * CPX;
  const float* xin = mats + (size_t)(1 + 2 * s) * NC;
  float* xout = mats + (size_t)(2 + 2 * s) * NC;

  const int* rs = row_start + s * (NN + 1);
  const int* cs = cols + s * NNZE;
  const float* vs = vals + s * NNZE;
  const int start = rs[r], end = rs[r + 1];

  float4 acc = {0.f, 0.f, 0.f, 0.f};
  for (int e = start; e < end; ++e) {
    int col = cs[e];
    float v = vs[e];
    float4 x = *(const float4*)(xin + (size_t)col * CPX + tid * 4);
    acc.x += v * x.x; acc.y += v * x.y; acc.z += v * x.z; acc.w += v * x.w;
  }
  float4 p = *(const float4*)(mats + (size_t)r * CPX + tid * 4);  // x0 row
  float4 o;
  o.x = 2.f * acc.x - p.x; o.y = 2.f * acc.y - p.y;
  o.z = 2.f * acc.z - p.z; o.w = 2.f * acc.w - p.w;
  *(float4*)(xout + (size_t)r * CPX + tid * 4) = o;
}

// ---------------- double-buffered fp32 GEMM with fused epilogue ----------------
// A[bn][K] with K = 5*FPP (mats, padded, zero-filled pads); W = Wp[K][JJ].
// MODE 0: gatesOut[bn][jj] = sigmoid(.)  (JJ=128, grid.y = 2)
// MODE 1: c = tanh(.); u = gatesIn[bn][H+jj]; ns = u*s+(1-u)*c -> state, outT (JJ=64)
template <int MODE, int BM, int TM, int FPP, int JJ>
__global__ __launch_bounds__(256) void gemm_kernel(
    const float* __restrict__ mats, const float* __restrict__ Wp, const float* __restrict__ bias,
    float* __restrict__ gatesOut, const float* __restrict__ gatesIn,
    float* __restrict__ state, float* __restrict__ outT) {
  constexpr int KT = 32;
  constexpr int BN = 64;
  constexpr int LDA = 36;              // row stride (floats): 16B-aligned, <=2-way banks
  constexpr int CP = BB * FPP;
  constexpr int NPH = MM * (FPP / KT);
  constexpr int A_PER_T = BM * KT / 256;  // 8 (BM=64) or 4 (BM=32)

  __shared__ float As[2][BM][LDA];
  __shared__ float Ws[2][KT][BN];

  const int tid = threadIdx.x;
  const int tx = tid & 15;
  const int ty = tid >> 4;
  const int bn0 = blockIdx.x * BM;
  const int jb0 = blockIdx.y * BN;
  const int nB = bn0 >> 10;            // batch index (tile never straddles batches)
  const int n0 = bn0 & (NN - 1);

  const int arow = (BM == 64) ? (tid >> 2) : (tid >> 3);
  const int acol = (BM == 64) ? ((tid & 3) * 8) : ((tid & 7) * 4);
  const int wrow = tid >> 3;
  const int wcol = (tid & 7) * 8;

  float ast[A_PER_T];
  float wst[8];

  auto gload = [&](int ph) {
    int m = ph / (FPP / KT);
    int f0 = (ph - m * (FPP / KT)) * KT;
    const float* abase =
        mats + (size_t)m * NN * CP + (size_t)(n0 + arow) * CP + nB * FPP + f0 + acol;
    *(float4*)&ast[0] = *(const float4*)abase;
    if constexpr (A_PER_T == 8) *(float4*)&ast[4] = *(const float4*)(abase + 4);
    const float* wbase = Wp + (size_t)(m * FPP + f0 + wrow) * JJ + jb0 + wcol;
    *(float4*)&wst[0] = *(const float4*)wbase;
    *(float4*)&wst[4] = *(const float4*)(wbase + 4);
  };
  auto stos = [&](int buf) {
    *(float4*)&As[buf][arow][acol] = *(float4*)&ast[0];
    if constexpr (A_PER_T == 8) *(float4*)&As[buf][arow][acol + 4] = *(float4*)&ast[4];
    *(float4*)&Ws[buf][wrow][wcol] = *(float4*)&wst[0];
    *(float4*)&Ws[buf][wrow][wcol + 4] = *(float4*)&wst[4];
  };

  float acc[TM][4] = {};

  gload(0);
  stos(0);
  __syncthreads();

  for (int ph = 0; ph < NPH; ++ph) {
    const int cur = ph & 1;
    if (ph + 1 < NPH) gload(ph + 1);
#pragma unroll
    for (int k = 0; k < KT; k += 4) {
      float a4[TM][4], w4[4][4];
#pragma unroll
      for (int i = 0; i < TM; ++i)
        *(float4*)a4[i] = *(const float4*)&As[cur][ty + i * 16][k];
#pragma unroll
      for (int q = 0; q < 4; ++q)
        *(float4*)w4[q] = *(const float4*)&Ws[cur][k + q][tx * 4];
#pragma unroll
      for (int q = 0; q < 4; ++q)
#pragma unroll
        for (int i = 0; i < TM; ++i)
#pragma unroll
          for (int j = 0; j < 4; ++j) acc[i][j] += a4[i][q] * w4[q][j];
    }
    if (ph + 1 < NPH) {
      stos(cur ^ 1);      // writes other buffer: safe w.r.t. concurrent reads of cur
      __syncthreads();    // one barrier per phase
    }
  }

#pragma unroll
  for (int i = 0; i < TM; ++i) {
    int bn = bn0 + ty + i * 16;
    int n = bn & (NN - 1);
    int b = bn >> 10;
#pragma unroll
    for (int j = 0; j < 4; ++j) {
      int jj = jb0 + tx * 4 + j;
      float v = acc[i][j] + bias[jj];
      if (MODE == 0) {
        v = 1.f / (1.f + expf(-v));
        gatesOut[(size_t)bn * (2 * HH) + jj] = v;
      } else {
        float c = tanhf(v);
        float u = gatesIn[(size_t)bn * (2 * HH) + HH + jj];
        size_t si = (size_t)b * (NN * HH) + (size_t)n * HH + jj;
        float s = state[si];
        float ns = u * s + (1.f - u) * c;
        state[si] = ns;
        outT[si] = ns;
      }
    }
  }
}

// ---------------- host orchestration ----------------
extern "C" void kernel_launch(void* const* d_in, const int* in_sizes, int n_in, void* d_out,
                              int out_size, void* d_ws, size_t ws_size, hipStream_t stream) {
  const float* inputs = (const float*)d_in[0];
  const float* init_h = (const float*)d_in[1];
  const int* sup_rows = (const int*)d_in[2];
  const int* sup_cols = (const int*)d_in[3];
  const float* sup_vals = (const float*)d_in[4];
  const float* Wg[2] = {(const float*)d_in[5], (const float*)d_in[9]};
  const float* bg[2] = {(const float*)d_in[6], (const float*)d_in[10]};
  const float* Wc[2] = {(const float*)d_in[7], (const float*)d_in[11]};
  const float* bc[2] = {(const float*)d_in[8], (const float*)d_in[12]};

  float* out_h = (float*)d_out;                  // [L][B*N*H] final hidden states
  float* out_cur = out_h + (size_t)LL * BNH;     // [T][B*N*H] layer-1 outputs

  char* p = (char*)d_ws;
  auto alloc = [&](size_t bytes) -> void* {
    void* r = (void*)p;
    p += (bytes + 255) & ~(size_t)255;
    return r;
  };
  int* colsS = (int*)alloc(2 * NNZE * sizeof(int));
  float* valsS = (float*)alloc(2 * NNZE * sizeof(float));
  int* row_start = (int*)alloc(2 * (NN + 1) * sizeof(int));
  int* cursor = (int*)alloc(2 * NN * sizeof(int));
  int* counts = (int*)alloc(2 * NN * sizeof(int));
  float* Wgp[2];
  float* Wcp[2];
  Wgp[0] = (float*)alloc((size_t)MM * FP0 * 128 * sizeof(float));
  Wcp[0] = (float*)alloc((size_t)MM * FP0 * 64 * sizeof(float));
  Wgp[1] = (float*)alloc((size_t)MM * FP1 * 128 * sizeof(float));
  Wcp[1] = (float*)alloc((size_t)MM * FP1 * 64 * sizeof(float));
  float* mats = (float*)alloc((size_t)MM * NN * CP1 * sizeof(float));     // 20 MB
  float* gatesBuf = (float*)alloc((size_t)BB * NN * 128 * sizeof(float)); // 4 MB
  float* x01 = (float*)alloc(BNH * sizeof(float));                        // 2 MB

  // --- CSR build ---
  zero_int_kernel<<<(2 * NN + 255) / 256, 256, 0, stream>>>(counts, 2 * NN);
  csr_count_kernel<<<(2 * NNZE + 255) / 256, 256, 0, stream>>>(sup_rows, counts);
  csr_scan_kernel<<<2, NN, 0, stream>>>(counts, row_start, cursor);
  csr_scatter_kernel<<<(2 * NNZE + 255) / 256, 256, 0, stream>>>(sup_rows, sup_cols, sup_vals,
                                                                 cursor, colsS, valsS);
  // --- permute + pad weights ---
  permw_kernel<<<(MM * FP0 * 128 + 255) / 256, 256, 0, stream>>>(Wg[0], Wgp[0], 66, FP0, 128);
  permw_kernel<<<(MM * FP0 * 64 + 255) / 256, 256, 0, stream>>>(Wc[0], Wcp[0], 66, FP0, 64);
  permw_kernel<<<(MM * FP1 * 128 + 255) / 256, 256, 0, stream>>>(Wg[1], Wgp[1], 128, FP1, 128);
  permw_kernel<<<(MM * FP1 * 64 + 255) / 256, 256, 0, stream>>>(Wc[1], Wcp[1], 128, FP1, 64);
  // --- init states (live in d_out) ---
  copy_kernel<<<((int)(LL * BNH) + 255) / 256, 256, 0, stream>>>(init_h, out_h, (int)(LL * BNH));

  for (int t = 0; t < TT; ++t) {
    // ---- layer 0 ----
    {
      float* state = out_h;
      const float* xi = inputs + (size_t)t * BB * NN * INDIM;
      float* outT = x01;
      spmm1_l0_kernel<0><<<dim3(NN, 2), 256, 0, stream>>>(row_start, colsS, valsS, xi, state,
                                                          nullptr, mats);
      spmm2_kernel<CP0><<<dim3(NN, 2), 256, 0, stream>>>(row_start, colsS, valsS, mats);
      gemm_kernel<0, 64, 4, FP0, 128><<<dim3(BB * NN / 64, 2), 256, 0, stream>>>(
          mats, Wgp[0], bg[0], gatesBuf, nullptr, nullptr, nullptr);
      spmm1_l0_kernel<1><<<dim3(NN, 2), 256, 0, stream>>>(row_start, colsS, valsS, xi, state,
                                                          gatesBuf, mats);
      spmm2_kernel<CP0><<<dim3(NN, 2), 256, 0, stream>>>(row_start, colsS, valsS, mats);
      gemm_kernel<1, 32, 2, FP0, 64><<<dim3(BB * NN / 32, 1), 256, 0, stream>>>(
          mats, Wcp[0], bc[0], nullptr, gatesBuf, state, outT);
    }
    // ---- layer 1 ----
    {
      float* state = out_h + BNH;
      const float* xi = x01;
      float* outT = out_cur + (size_t)t * BNH;
      spmm1_l1_kernel<0><<<dim3(NN, 2), 256, 0, stream>>>(row_start, colsS, valsS, xi, state,
                                                          nullptr, mats);
      spmm2_kernel<CP1><<<dim3(NN, 2), 256, 0, stream>>>(row_start, colsS, valsS, mats);
      gemm_kernel<0, 64, 4, FP1, 128><<<dim3(BB * NN / 64, 2), 256, 0, stream>>>(
          mats, Wgp[1], bg[1], gatesBuf, nullptr, nullptr, nullptr);
      spmm1_l1_kernel<1><<<dim3(NN, 2), 256, 0, stream>>>(row_start, colsS, valsS, xi, state,
                                                          gatesBuf, mats);
      spmm2_kernel<CP1><<<dim3(NN, 2), 256, 0, stream>>>(row_start, colsS, valsS, mats);
      gemm_kernel<1, 32, 2, FP1, 64><<<dim3(BB * NN / 32, 1), 256, 0, stream>>>(
          mats, Wcp[1], bc[1], nullptr, gatesBuf, state, outT);
    }
  }
}

// Round 5
// 2914.279 us; speedup vs baseline: 1.7246x; 1.3049x over previous
//
#include <hip/hip_runtime.h>
#include <hip/hip_bf16.h>
#include <math.h>

// Problem constants (fixed by the reference)
#define NN 1024
#define HH 64
#define TT 12
#define BB 8
#define INDIM 2
#define LL 2
#define NNZE 16384
#define MM 5

// Padded per-mat feature dims (K-dim per diffusion matrix), multiple of 32
#define FP0 96    // layer0: F = 66 -> 96 (pad zero)
#define FP1 128   // layer1: F = 128
#define CP0 (BB * FP0)   // 768
#define CP1 (BB * FP1)   // 1024

static constexpr size_t BNH = (size_t)BB * NN * HH;  // 524288

typedef short bf16x8 __attribute__((ext_vector_type(8)));
typedef float f32x4 __attribute__((ext_vector_type(4)));

// ---------------- small utility kernels ----------------
__global__ void zero_int_kernel(int* p, int n) {
  int i = blockIdx.x * blockDim.x + threadIdx.x;
  if (i < n) p[i] = 0;
}

__global__ void copy_kernel(const float* __restrict__ src, float* __restrict__ dst, int n) {
  int i = blockIdx.x * blockDim.x + threadIdx.x;
  if (i < n) dst[i] = src[i];
}

// ---------------- CSR build (per support) ----------------
__global__ void csr_count_kernel(const int* __restrict__ rows, int* __restrict__ counts) {
  int i = blockIdx.x * blockDim.x + threadIdx.x;
  if (i < 2 * NNZE) {
    int s = i / NNZE;
    atomicAdd(&counts[s * NN + rows[i]], 1);
  }
}

__global__ void csr_scan_kernel(const int* __restrict__ counts, int* __restrict__ row_start,
                                int* __restrict__ cursor) {
  __shared__ int bufA[NN];
  __shared__ int bufB[NN];
  int s = blockIdx.x;
  int t = threadIdx.x;
  bufA[t] = counts[s * NN + t];
  __syncthreads();
  int* src = bufA;
  int* dst = bufB;
  for (int off = 1; off < NN; off <<= 1) {
    dst[t] = src[t] + (t >= off ? src[t - off] : 0);
    __syncthreads();
    int* tmp = src; src = dst; dst = tmp;
  }
  row_start[s * (NN + 1) + t + 1] = src[t];
  cursor[s * NN + t] = (t == 0) ? 0 : src[t - 1];
  if (t == 0) row_start[s * (NN + 1)] = 0;
}

__global__ void csr_scatter_kernel(const int* __restrict__ rows, const int* __restrict__ colsIn,
                                   const float* __restrict__ valsIn, int* __restrict__ cursor,
                                   int* __restrict__ colsOut, float* __restrict__ valsOut) {
  int i = blockIdx.x * blockDim.x + threadIdx.x;
  if (i < 2 * NNZE) {
    int s = i / NNZE;
    int r = rows[i];
    int pos = atomicAdd(&cursor[s * NN + r], 1);
    colsOut[s * NNZE + pos] = colsIn[i];
    valsOut[s * NNZE + pos] = valsIn[i];
  }
}

// ---------------- weight permute + transpose + bf16 hi/lo split ----------------
// WT[j][k_total] with k_total = m*Fp + f; source W[(f*M + m)*J + j]; pads (f>=F) zero.
__global__ void permwT_kernel(const float* __restrict__ W, unsigned short* __restrict__ WTh,
                              unsigned short* __restrict__ WTl, int F, int Fp, int J) {
  int Ktot = MM * Fp;
  int total = J * Ktot;
  for (int idx = blockIdx.x * blockDim.x + threadIdx.x; idx < total;
       idx += gridDim.x * blockDim.x) {
    int k = idx % Ktot;
    int j = idx / Ktot;
    int m = k / Fp;
    int f = k - m * Fp;
    float x = (f < F) ? W[(size_t)(f * MM + m) * J + j] : 0.f;
    unsigned u = __float_as_uint(x);
    unsigned short h = (unsigned short)(u >> 16);
    float hf = __uint_as_float(u & 0xFFFF0000u);
    WTh[idx] = h;
    WTl[idx] = (unsigned short)(__float_as_uint(x - hf) >> 16);
  }
}

// ---------------- fused x0-build + hop1, layer1 (Fin=64, Fp=128) ----------------
template <int MODE>
__global__ __launch_bounds__(256) void spmm1_l1_kernel(
    const int* __restrict__ row_start, const int* __restrict__ cols,
    const float* __restrict__ vals, const float* __restrict__ xi,   // [B][N][64]
    const float* __restrict__ state,                                 // [B][N][64]
    const float* __restrict__ gates,                                 // [B*N][128]
    float* __restrict__ mats) {
  const int r = blockIdx.x, s = blockIdx.y, tid = threadIdx.x;
  const int b = tid >> 5;
  const int f = (tid & 31) * 4;
  const bool isX = (f < HH);
  const float* src = isX ? xi : state;
  const size_t srcBase = (size_t)b * NN * HH + (isX ? f : f - HH);
  const size_t gBase = (size_t)b * NN * (2 * HH) + (f - HH);

  const int* rs = row_start + s * (NN + 1);
  const int* cs = cols + s * NNZE;
  const float* vs = vals + s * NNZE;
  const int start = rs[r], end = rs[r + 1];

  float4 acc = {0.f, 0.f, 0.f, 0.f};
  for (int e = start; e < end; ++e) {
    int col = cs[e];
    float v = vs[e];
    float4 x = *(const float4*)(src + srcBase + (size_t)col * HH);
    if (MODE && !isX) {
      float4 g = *(const float4*)(gates + gBase + (size_t)col * (2 * HH));
      x.x *= g.x; x.y *= g.y; x.z *= g.z; x.w *= g.w;
    }
    acc.x += v * x.x; acc.y += v * x.y; acc.z += v * x.z; acc.w += v * x.w;
  }
  *(float4*)(mats + (size_t)(1 + 2 * s) * (NN * CP1) + (size_t)r * CP1 + tid * 4) = acc;

  if (s == 0) {
    float4 x = *(const float4*)(src + srcBase + (size_t)r * HH);
    if (MODE && !isX) {
      float4 g = *(const float4*)(gates + gBase + (size_t)r * (2 * HH));
      x.x *= g.x; x.y *= g.y; x.z *= g.z; x.w *= g.w;
    }
    *(float4*)(mats + (size_t)r * CP1 + tid * 4) = x;
  }
}

// ---------------- fused x0-build + hop1, layer0 (Fin=2, Fp=96) ----------------
template <int MODE>
__global__ __launch_bounds__(256) void spmm1_l0_kernel(
    const int* __restrict__ row_start, const int* __restrict__ cols,
    const float* __restrict__ vals, const float* __restrict__ xi,   // [B][N][2]
    const float* __restrict__ state,                                 // [B][N][64]
    const float* __restrict__ gates,                                 // [B*N][128]
    float* __restrict__ mats) {
  const int tid = threadIdx.x;
  if (tid >= CP0 / 4) return;
  const int r = blockIdx.x, s = blockIdx.y;
  const int c4 = tid * 4;
  const int b = c4 / FP0;
  const int f = c4 - b * FP0;

  int kind[4];
  size_t sb[4], gb[4];
#pragma unroll
  for (int q = 0; q < 4; ++q) {
    int fe = f + q;
    if (fe < INDIM) {
      kind[q] = 0;
      sb[q] = (size_t)b * NN * INDIM + fe;
      gb[q] = 0;
    } else if (fe < INDIM + HH) {
      kind[q] = 1;
      int h = fe - INDIM;
      sb[q] = (size_t)b * NN * HH + h;
      gb[q] = (size_t)b * NN * (2 * HH) + h;
    } else {
      kind[q] = 2;
      sb[q] = gb[q] = 0;
    }
  }

  const int* rs = row_start + s * (NN + 1);
  const int* cs = cols + s * NNZE;
  const float* vs = vals + s * NNZE;
  const int start = rs[r], end = rs[r + 1];

  float acc[4] = {0.f, 0.f, 0.f, 0.f};
  for (int e = start; e < end; ++e) {
    int col = cs[e];
    float v = vs[e];
#pragma unroll
    for (int q = 0; q < 4; ++q) {
      float x;
      if (kind[q] == 0) {
        x = xi[sb[q] + (size_t)col * INDIM];
      } else if (kind[q] == 1) {
        x = state[sb[q] + (size_t)col * HH];
        if (MODE) x *= gates[gb[q] + (size_t)col * (2 * HH)];
      } else {
        continue;
      }
      acc[q] += v * x;
    }
  }
  float4 av;
  av.x = acc[0]; av.y = acc[1]; av.z = acc[2]; av.w = acc[3];
  *(float4*)(mats + (size_t)(1 + 2 * s) * (NN * CP0) + (size_t)r * CP0 + c4) = av;

  if (s == 0) {
    float x0v[4];
#pragma unroll
    for (int q = 0; q < 4; ++q) {
      float x = 0.f;
      if (kind[q] == 0) {
        x = xi[sb[q] + (size_t)r * INDIM];
      } else if (kind[q] == 1) {
        x = state[sb[q] + (size_t)r * HH];
        if (MODE) x *= gates[gb[q] + (size_t)r * (2 * HH)];
      }
      x0v[q] = x;
    }
    float4 xv;
    xv.x = x0v[0]; xv.y = x0v[1]; xv.z = x0v[2]; xv.w = x0v[3];
    *(float4*)(mats + (size_t)r * CP0 + c4) = xv;
  }
}

// ---------------- hop2: x2 = 2*A@x1 - x0 ----------------
template <int CPX>
__global__ __launch_bounds__(256) void spmm2_kernel(
    const int* __restrict__ row_start, const int* __restrict__ cols,
    const float* __restrict__ vals, float* __restrict__ mats) {
  const int tid = threadIdx.x;
  if (tid * 4 >= CPX) return;
  const int r = blockIdx.x, s = blockIdx.y;
  const size_t NC = (size_t)NN * CPX;
  const float* xin = mats + (size_t)(1 + 2 * s) * NC;
  float* xout = mats + (size_t)(2 + 2 * s) * NC;

  const int* rs = row_start + s * (NN + 1);
  const int* cs = cols + s * NNZE;
  const float* vs = vals + s * NNZE;
  const int start = rs[r], end = rs[r + 1];

  float4 acc = {0.f, 0.f, 0.f, 0.f};
  for (int e = start; e < end; ++e) {
    int col = cs[e];
    float v = vs[e];
    float4 x = *(const float4*)(xin + (size_t)col * CPX + tid * 4);
    acc.x += v * x.x; acc.y += v * x.y; acc.z += v * x.z; acc.w += v * x.w;
  }
  float4 p = *(const float4*)(mats + (size_t)r * CPX + tid * 4);
  float4 o;
  o.x = 2.f * acc.x - p.x; o.y = 2.f * acc.y - p.y;
  o.z = 2.f * acc.z - p.z; o.w = 2.f * acc.w - p.w;
  *(float4*)(xout + (size_t)r * CPX + tid * 4) = o;
}

// ---------------- MFMA bf16x3 GEMM with fused epilogue ----------------
// out[bn][j] = sum_k A[bn][k] * W[k][j], A = mats fp32 (split to bf16 hi/lo at staging),
// W = precomputed transposed bf16 planes WTh/WTl [j][ktot].
// A*W ~= Ah*Wh + Ah*Wl + Al*Wh  (lo*lo dropped, ~2^-16 rel), fp32 MFMA accumulation.
// Tile 64x64 (bn x j), 4 waves in 2x2 grid, each wave 32x32 = 2x2 MFMA 16x16 tiles.
// MODE 0: gatesOut[bn][jj] = sigmoid(.+bias)   (JJ=128, grid.y=2)
// MODE 1: c=tanh(.+bias); u=gatesIn[bn][H+jj]; ns=u*s+(1-u)*c -> state, outT (JJ=64)
template <int MODE, int FPP, int JJ>
__global__ __launch_bounds__(256) void gemm_mfma_kernel(
    const float* __restrict__ mats, const unsigned short* __restrict__ WTh,
    const unsigned short* __restrict__ WTl, const float* __restrict__ bias,
    float* __restrict__ gatesOut, const float* __restrict__ gatesIn,
    float* __restrict__ state, float* __restrict__ outT) {
  constexpr int KT = 32;
  constexpr int LDR = 56;   // LDS row stride in bf16: 112 B -> 16B-aligned, ~2-4 way banks
  constexpr int CP = BB * FPP;
  constexpr int KTOT = MM * FPP;
  constexpr int NPH = KTOT / KT;

  __shared__ unsigned short As[2][2][64][LDR];  // [buf][plane hi/lo][row][k]
  __shared__ unsigned short Ws[2][2][64][LDR];  // [buf][plane][j][k]

  const int tid = threadIdx.x;
  const int lane = tid & 63;
  const int wid = tid >> 6;
  const int wr = wid >> 1, wc = wid & 1;      // wave 2x2 grid
  const int lr = lane & 15, g = lane >> 4;    // fragment row/col + k-group

  const int bn0 = blockIdx.x * 64;
  const int jb0 = blockIdx.y * 64;
  const int nB = bn0 >> 10;                    // batch (tile never straddles batches)
  const int n0 = bn0 & (NN - 1);

  // staging: thread t handles row t>>2, k-chunk (t&3)*8 (8 elems)
  const int srow = tid >> 2;
  const int scol = (tid & 3) * 8;

  float av[8];
  uint4 wh, wl;

  auto gload = [&](int ph) {
    const int m = (ph * KT) / FPP;
    const int f0 = (ph * KT) - m * FPP;
    const float* ab =
        mats + (size_t)m * NN * CP + (size_t)(n0 + srow) * CP + nB * FPP + f0 + scol;
    *(float4*)&av[0] = *(const float4*)ab;
    *(float4*)&av[4] = *(const float4*)(ab + 4);
    const size_t woff = (size_t)(jb0 + srow) * KTOT + ph * KT + scol;
    wh = *(const uint4*)(WTh + woff);
    wl = *(const uint4*)(WTl + woff);
  };
  auto stos = [&](int buf) {
    unsigned short h8[8], l8[8];
#pragma unroll
    for (int q = 0; q < 8; ++q) {
      float x = av[q];
      unsigned u = __float_as_uint(x);
      h8[q] = (unsigned short)(u >> 16);
      float hf = __uint_as_float(u & 0xFFFF0000u);
      l8[q] = (unsigned short)(__float_as_uint(x - hf) >> 16);
    }
    *(uint4*)&As[buf][0][srow][scol] = *(uint4*)h8;
    *(uint4*)&As[buf][1][srow][scol] = *(uint4*)l8;
    *(uint4*)&Ws[buf][0][srow][scol] = wh;
    *(uint4*)&Ws[buf][1][srow][scol] = wl;
  };

  f32x4 acc[2][2] = {};

  auto domfma = [&](int cur) {
    bf16x8 a[2][2], b[2][2];
#pragma unroll
    for (int tr = 0; tr < 2; ++tr)
#pragma unroll
      for (int pl = 0; pl < 2; ++pl)
        a[tr][pl] = *(const bf16x8*)&As[cur][pl][wr * 32 + tr * 16 + lr][g * 8];
#pragma unroll
    for (int tc = 0; tc < 2; ++tc)
#pragma unroll
      for (int pl = 0; pl < 2; ++pl)
        b[tc][pl] = *(const bf16x8*)&Ws[cur][pl][wc * 32 + tc * 16 + lr][g * 8];
#pragma unroll
    for (int tr = 0; tr < 2; ++tr)
#pragma unroll
      for (int tc = 0; tc < 2; ++tc) {
        acc[tr][tc] =
            __builtin_amdgcn_mfma_f32_16x16x32_bf16(a[tr][0], b[tc][0], acc[tr][tc], 0, 0, 0);
        acc[tr][tc] =
            __builtin_amdgcn_mfma_f32_16x16x32_bf16(a[tr][0], b[tc][1], acc[tr][tc], 0, 0, 0);
        acc[tr][tc] =
            __builtin_amdgcn_mfma_f32_16x16x32_bf16(a[tr][1], b[tc][0], acc[tr][tc], 0, 0, 0);
      }
  };

  gload(0);
  stos(0);
  __syncthreads();

  for (int ph = 0; ph < NPH; ++ph) {
    const int cur = ph & 1;
    if (ph + 1 < NPH) gload(ph + 1);
    domfma(cur);
    if (ph + 1 < NPH) {
      stos(cur ^ 1);    // other buffer: no race with current reads
      __syncthreads();  // one barrier per phase
    }
  }

  // epilogue: C/D frag mapping col = lane&15, row = (lane>>4)*4 + reg  [verified]
#pragma unroll
  for (int tr = 0; tr < 2; ++tr)
#pragma unroll
    for (int tc = 0; tc < 2; ++tc) {
      const int jj = jb0 + wc * 32 + tc * 16 + lr;
      const float bs = bias[jj];
#pragma unroll
      for (int q = 0; q < 4; ++q) {
        const int bn = bn0 + wr * 32 + tr * 16 + g * 4 + q;
        float v = acc[tr][tc][q] + bs;
        if (MODE == 0) {
          gatesOut[(size_t)bn * (2 * HH) + jj] = 1.f / (1.f + expf(-v));
        } else {
          const int n = bn & (NN - 1);
          const int b = bn >> 10;
          float c = tanhf(v);
          float u = gatesIn[(size_t)bn * (2 * HH) + HH + jj];
          size_t si = (size_t)b * (NN * HH) + (size_t)n * HH + jj;
          float s = state[si];
          float ns = u * s + (1.f - u) * c;
          state[si] = ns;
          outT[si] = ns;
        }
      }
    }
}

// ---------------- host orchestration ----------------
extern "C" void kernel_launch(void* const* d_in, const int* in_sizes, int n_in, void* d_out,
                              int out_size, void* d_ws, size_t ws_size, hipStream_t stream) {
  const float* inputs = (const float*)d_in[0];
  const float* init_h = (const float*)d_in[1];
  const int* sup_rows = (const int*)d_in[2];
  const int* sup_cols = (const int*)d_in[3];
  const float* sup_vals = (const float*)d_in[4];
  const float* Wg[2] = {(const float*)d_in[5], (const float*)d_in[9]};
  const float* bg[2] = {(const float*)d_in[6], (const float*)d_in[10]};
  const float* Wc[2] = {(const float*)d_in[7], (const float*)d_in[11]};
  const float* bc[2] = {(const float*)d_in[8], (const float*)d_in[12]};

  float* out_h = (float*)d_out;                  // [L][B*N*H] final hidden states
  float* out_cur = out_h + (size_t)LL * BNH;     // [T][B*N*H] layer-1 outputs

  char* p = (char*)d_ws;
  auto alloc = [&](size_t bytes) -> void* {
    void* r = (void*)p;
    p += (bytes + 255) & ~(size_t)255;
    return r;
  };
  int* colsS = (int*)alloc(2 * NNZE * sizeof(int));
  float* valsS = (float*)alloc(2 * NNZE * sizeof(float));
  int* row_start = (int*)alloc(2 * (NN + 1) * sizeof(int));
  int* cursor = (int*)alloc(2 * NN * sizeof(int));
  int* counts = (int*)alloc(2 * NN * sizeof(int));
  const int K0 = MM * FP0, K1 = MM * FP1;  // 480, 640
  unsigned short* WgTh[2];
  unsigned short* WgTl[2];
  unsigned short* WcTh[2];
  unsigned short* WcTl[2];
  WgTh[0] = (unsigned short*)alloc((size_t)128 * K0 * 2);
  WgTl[0] = (unsigned short*)alloc((size_t)128 * K0 * 2);
  WcTh[0] = (unsigned short*)alloc((size_t)64 * K0 * 2);
  WcTl[0] = (unsigned short*)alloc((size_t)64 * K0 * 2);
  WgTh[1] = (unsigned short*)alloc((size_t)128 * K1 * 2);
  WgTl[1] = (unsigned short*)alloc((size_t)128 * K1 * 2);
  WcTh[1] = (unsigned short*)alloc((size_t)64 * K1 * 2);
  WcTl[1] = (unsigned short*)alloc((size_t)64 * K1 * 2);
  float* mats = (float*)alloc((size_t)MM * NN * CP1 * sizeof(float));     // 20 MB
  float* gatesBuf = (float*)alloc((size_t)BB * NN * 128 * sizeof(float)); // 4 MB
  float* x01 = (float*)alloc(BNH * sizeof(float));                        // 2 MB

  // --- CSR build ---
  zero_int_kernel<<<(2 * NN + 255) / 256, 256, 0, stream>>>(counts, 2 * NN);
  csr_count_kernel<<<(2 * NNZE + 255) / 256, 256, 0, stream>>>(sup_rows, counts);
  csr_scan_kernel<<<2, NN, 0, stream>>>(counts, row_start, cursor);
  csr_scatter_kernel<<<(2 * NNZE + 255) / 256, 256, 0, stream>>>(sup_rows, sup_cols, sup_vals,
                                                                 cursor, colsS, valsS);
  // --- permute + transpose + bf16-split weights (one-time; weights static) ---
  permwT_kernel<<<(128 * K0 + 255) / 256, 256, 0, stream>>>(Wg[0], WgTh[0], WgTl[0], 66, FP0, 128);
  permwT_kernel<<<(64 * K0 + 255) / 256, 256, 0, stream>>>(Wc[0], WcTh[0], WcTl[0], 66, FP0, 64);
  permwT_kernel<<<(128 * K1 + 255) / 256, 256, 0, stream>>>(Wg[1], WgTh[1], WgTl[1], 128, FP1, 128);
  permwT_kernel<<<(64 * K1 + 255) / 256, 256, 0, stream>>>(Wc[1], WcTh[1], WcTl[1], 128, FP1, 64);
  // --- init states (live in d_out) ---
  copy_kernel<<<((int)(LL * BNH) + 255) / 256, 256, 0, stream>>>(init_h, out_h, (int)(LL * BNH));

  for (int t = 0; t < TT; ++t) {
    // ---- layer 0 ----
    {
      float* state = out_h;
      const float* xi = inputs + (size_t)t * BB * NN * INDIM;
      float* outT = x01;
      spmm1_l0_kernel<0><<<dim3(NN, 2), 256, 0, stream>>>(row_start, colsS, valsS, xi, state,
                                                          nullptr, mats);
      spmm2_kernel<CP0><<<dim3(NN, 2), 256, 0, stream>>>(row_start, colsS, valsS, mats);
      gemm_mfma_kernel<0, FP0, 128><<<dim3(BB * NN / 64, 2), 256, 0, stream>>>(
          mats, WgTh[0], WgTl[0], bg[0], gatesBuf, nullptr, nullptr, nullptr);
      spmm1_l0_kernel<1><<<dim3(NN, 2), 256, 0, stream>>>(row_start, colsS, valsS, xi, state,
                                                          gatesBuf, mats);
      spmm2_kernel<CP0><<<dim3(NN, 2), 256, 0, stream>>>(row_start, colsS, valsS, mats);
      gemm_mfma_kernel<1, FP0, 64><<<dim3(BB * NN / 64, 1), 256, 0, stream>>>(
          mats, WcTh[0], WcTl[0], bc[0], nullptr, gatesBuf, state, outT);
    }
    // ---- layer 1 ----
    {
      float* state = out_h + BNH;
      const float* xi = x01;
      float* outT = out_cur + (size_t)t * BNH;
      spmm1_l1_kernel<0><<<dim3(NN, 2), 256, 0, stream>>>(row_start, colsS, valsS, xi, state,
                                                          nullptr, mats);
      spmm2_kernel<CP1><<<dim3(NN, 2), 256, 0, stream>>>(row_start, colsS, valsS, mats);
      gemm_mfma_kernel<0, FP1, 128><<<dim3(BB * NN / 64, 2), 256, 0, stream>>>(
          mats, WgTh[1], WgTl[1], bg[1], gatesBuf, nullptr, nullptr, nullptr);
      spmm1_l1_kernel<1><<<dim3(NN, 2), 256, 0, stream>>>(row_start, colsS, valsS, xi, state,
                                                          gatesBuf, mats);
      spmm2_kernel<CP1><<<dim3(NN, 2), 256, 0, stream>>>(row_start, colsS, valsS, mats);
      gemm_mfma_kernel<1, FP1, 64><<<dim3(BB * NN / 64, 1), 256, 0, stream>>>(
          mats, WcTh[1], WcTl[1], bc[1], nullptr, gatesBuf, state, outT);
    }
  }
}

// Round 6
// 2036.939 us; speedup vs baseline: 2.4674x; 1.4307x over previous
//
#include <hip/hip_runtime.h>
#include <hip/hip_bf16.h>
#include <math.h>

// Problem constants (fixed by the reference)
#define NN 1024
#define HH 64
#define TT 12
#define BB 8
#define INDIM 2
#define LL 2
#define NNZE 16384
#define MM 5

// Padded per-mat feature dims (K-dim per diffusion matrix), multiple of 32
// Layer-0 feature order (REORDERED): [state(64), xi(2), pad(30)] -> aligned float4 gathers
// Layer-1 feature order:             [xi(64), state(64)]
#define FP0 96
#define FP1 128
#define CP0 (BB * FP0)   // 768
#define CP1 (BB * FP1)   // 1024

static constexpr size_t BNH = (size_t)BB * NN * HH;  // 524288

typedef short bf16x8 __attribute__((ext_vector_type(8)));
typedef float f32x4 __attribute__((ext_vector_type(4)));

// ---------------- small utility kernels ----------------
__global__ void zero_int_kernel(int* p, int n) {
  int i = blockIdx.x * blockDim.x + threadIdx.x;
  if (i < n) p[i] = 0;
}

__global__ void copy_kernel(const float* __restrict__ src, float* __restrict__ dst, int n) {
  int i = blockIdx.x * blockDim.x + threadIdx.x;
  if (i < n) dst[i] = src[i];
}

// ---------------- CSR build (per support) ----------------
__global__ void csr_count_kernel(const int* __restrict__ rows, int* __restrict__ counts) {
  int i = blockIdx.x * blockDim.x + threadIdx.x;
  if (i < 2 * NNZE) {
    int s = i / NNZE;
    atomicAdd(&counts[s * NN + rows[i]], 1);
  }
}

__global__ void csr_scan_kernel(const int* __restrict__ counts, int* __restrict__ row_start,
                                int* __restrict__ cursor) {
  __shared__ int bufA[NN];
  __shared__ int bufB[NN];
  int s = blockIdx.x;
  int t = threadIdx.x;
  bufA[t] = counts[s * NN + t];
  __syncthreads();
  int* src = bufA;
  int* dst = bufB;
  for (int off = 1; off < NN; off <<= 1) {
    dst[t] = src[t] + (t >= off ? src[t - off] : 0);
    __syncthreads();
    int* tmp = src; src = dst; dst = tmp;
  }
  row_start[s * (NN + 1) + t + 1] = src[t];
  cursor[s * NN + t] = (t == 0) ? 0 : src[t - 1];
  if (t == 0) row_start[s * (NN + 1)] = 0;
}

__global__ void csr_scatter_kernel(const int* __restrict__ rows, const int* __restrict__ colsIn,
                                   const float* __restrict__ valsIn, int* __restrict__ cursor,
                                   int* __restrict__ colsOut, float* __restrict__ valsOut) {
  int i = blockIdx.x * blockDim.x + threadIdx.x;
  if (i < 2 * NNZE) {
    int s = i / NNZE;
    int r = rows[i];
    int pos = atomicAdd(&cursor[s * NN + r], 1);
    colsOut[s * NNZE + pos] = colsIn[i];
    valsOut[s * NNZE + pos] = valsIn[i];
  }
}

// ---------------- weight permute + transpose + bf16 hi/lo split ----------------
// WT[j][k_total], k_total = m*Fp + f_new.
// reord==0 (layer1): f_orig = f_new (identity; F=Fp=128)
// reord==1 (layer0): f_new<64 -> f_orig=f_new+2 (state); f_new in[64,66) -> f_orig=f_new-64 (xi);
//                    else pad(0)
__global__ void permwT_kernel(const float* __restrict__ W, unsigned short* __restrict__ WTh,
                              unsigned short* __restrict__ WTl, int F, int Fp, int J, int reord) {
  int Ktot = MM * Fp;
  int total = J * Ktot;
  for (int idx = blockIdx.x * blockDim.x + threadIdx.x; idx < total;
       idx += gridDim.x * blockDim.x) {
    int k = idx % Ktot;
    int j = idx / Ktot;
    int m = k / Fp;
    int fn = k - m * Fp;
    int fo;
    if (reord) {
      fo = (fn < HH) ? fn + INDIM : (fn < HH + INDIM ? fn - HH : -1);
    } else {
      fo = (fn < F) ? fn : -1;
    }
    float x = (fo >= 0) ? W[(size_t)(fo * MM + m) * J + j] : 0.f;
    unsigned u = __float_as_uint(x);
    unsigned short h = (unsigned short)(u >> 16);
    float hf = __uint_as_float(u & 0xFFFF0000u);
    WTh[idx] = h;
    WTl[idx] = (unsigned short)(__float_as_uint(x - hf) >> 16);
  }
}

// ---------------- fused x0-build + hop1, layer1 (Fin=64, Fp=128) ----------------
// MODE==1: xi columns persist from MODE 0 pass (diffusion is linear; xi part unchanged)
template <int MODE>
__global__ __launch_bounds__(256) void spmm1_l1_kernel(
    const int* __restrict__ row_start, const int* __restrict__ cols,
    const float* __restrict__ vals, const float* __restrict__ xi,   // [B][N][64]
    const float* __restrict__ state,                                 // [B][N][64]
    const float* __restrict__ gates,                                 // [B*N][128]
    float* __restrict__ mats) {
  const int r = blockIdx.x, s = blockIdx.y, tid = threadIdx.x;
  const int b = tid >> 5;
  const int f = (tid & 31) * 4;
  const bool isX = (f < HH);
  if (MODE && isX) return;  // xi diffusion already in mats from MODE 0
  const float* src = isX ? xi : state;
  const size_t srcBase = (size_t)b * NN * HH + (isX ? f : f - HH);
  const size_t gBase = (size_t)b * NN * (2 * HH) + (f - HH);

  const int* rs = row_start + s * (NN + 1);
  const int* cs = cols + s * NNZE;
  const float* vs = vals + s * NNZE;
  const int start = rs[r], end = rs[r + 1];

  float4 a0 = {0.f, 0.f, 0.f, 0.f}, a1 = {0.f, 0.f, 0.f, 0.f};
  int e = start;
  for (; e + 1 < end; e += 2) {
    int c0 = cs[e], c1 = cs[e + 1];
    float v0 = vs[e], v1 = vs[e + 1];
    float4 x0 = *(const float4*)(src + srcBase + (size_t)c0 * HH);
    float4 x1 = *(const float4*)(src + srcBase + (size_t)c1 * HH);
    if (MODE && !isX) {
      float4 g0 = *(const float4*)(gates + gBase + (size_t)c0 * (2 * HH));
      float4 g1 = *(const float4*)(gates + gBase + (size_t)c1 * (2 * HH));
      x0.x *= g0.x; x0.y *= g0.y; x0.z *= g0.z; x0.w *= g0.w;
      x1.x *= g1.x; x1.y *= g1.y; x1.z *= g1.z; x1.w *= g1.w;
    }
    a0.x += v0 * x0.x; a0.y += v0 * x0.y; a0.z += v0 * x0.z; a0.w += v0 * x0.w;
    a1.x += v1 * x1.x; a1.y += v1 * x1.y; a1.z += v1 * x1.z; a1.w += v1 * x1.w;
  }
  if (e < end) {
    int c0 = cs[e];
    float v0 = vs[e];
    float4 x0 = *(const float4*)(src + srcBase + (size_t)c0 * HH);
    if (MODE && !isX) {
      float4 g0 = *(const float4*)(gates + gBase + (size_t)c0 * (2 * HH));
      x0.x *= g0.x; x0.y *= g0.y; x0.z *= g0.z; x0.w *= g0.w;
    }
    a0.x += v0 * x0.x; a0.y += v0 * x0.y; a0.z += v0 * x0.z; a0.w += v0 * x0.w;
  }
  float4 o;
  o.x = a0.x + a1.x; o.y = a0.y + a1.y; o.z = a0.z + a1.z; o.w = a0.w + a1.w;
  *(float4*)(mats + (size_t)(1 + 2 * s) * (NN * CP1) + (size_t)r * CP1 + tid * 4) = o;

  if (s == 0) {  // materialize x0 row r
    float4 x = *(const float4*)(src + srcBase + (size_t)r * HH);
    if (MODE && !isX) {
      float4 g = *(const float4*)(gates + gBase + (size_t)r * (2 * HH));
      x.x *= g.x; x.y *= g.y; x.z *= g.z; x.w *= g.w;
    }
    *(float4*)(mats + (size_t)r * CP1 + tid * 4) = x;
  }
}

// ---------------- fused x0-build + hop1, layer0 (state-first layout) ----------------
// slots per batch: 24 (96/4). fn<64: state float4; fn==64: [xi0, xi1, 0, 0]; fn>=68: pads
template <int MODE>
__global__ __launch_bounds__(256) void spmm1_l0_kernel(
    const int* __restrict__ row_start, const int* __restrict__ cols,
    const float* __restrict__ vals, const float* __restrict__ xi,   // [B][N][2]
    const float* __restrict__ state,                                 // [B][N][64]
    const float* __restrict__ gates,                                 // [B*N][128]
    float* __restrict__ mats) {
  const int tid = threadIdx.x;
  constexpr int SLOTS = FP0 / 4;  // 24
  if (tid >= BB * SLOTS) return;  // 192 active
  const int r = blockIdx.x, s = blockIdx.y;
  const int b = tid / SLOTS;
  const int fn = (tid - b * SLOTS) * 4;
  const int c4 = b * FP0 + fn;

  float* x1p = mats + (size_t)(1 + 2 * s) * (NN * CP0) + (size_t)r * CP0 + c4;
  float* x0p = mats + (size_t)r * CP0 + c4;

  const int* rs = row_start + s * (NN + 1);
  const int* cs = cols + s * NNZE;
  const float* vs = vals + s * NNZE;
  const int start = rs[r], end = rs[r + 1];

  if (fn < HH) {
    // state gather (aligned float4)
    const float* sb = state + (size_t)b * NN * HH + fn;
    const float* gb = gates + (size_t)b * NN * (2 * HH) + fn;
    float4 a0 = {0.f, 0.f, 0.f, 0.f}, a1 = {0.f, 0.f, 0.f, 0.f};
    int e = start;
    for (; e + 1 < end; e += 2) {
      int c0 = cs[e], c1 = cs[e + 1];
      float v0 = vs[e], v1 = vs[e + 1];
      float4 x0 = *(const float4*)(sb + (size_t)c0 * HH);
      float4 x1 = *(const float4*)(sb + (size_t)c1 * HH);
      if (MODE) {
        float4 g0 = *(const float4*)(gb + (size_t)c0 * (2 * HH));
        float4 g1 = *(const float4*)(gb + (size_t)c1 * (2 * HH));
        x0.x *= g0.x; x0.y *= g0.y; x0.z *= g0.z; x0.w *= g0.w;
        x1.x *= g1.x; x1.y *= g1.y; x1.z *= g1.z; x1.w *= g1.w;
      }
      a0.x += v0 * x0.x; a0.y += v0 * x0.y; a0.z += v0 * x0.z; a0.w += v0 * x0.w;
      a1.x += v1 * x1.x; a1.y += v1 * x1.y; a1.z += v1 * x1.z; a1.w += v1 * x1.w;
    }
    if (e < end) {
      int c0 = cs[e];
      float v0 = vs[e];
      float4 x0 = *(const float4*)(sb + (size_t)c0 * HH);
      if (MODE) {
        float4 g0 = *(const float4*)(gb + (size_t)c0 * (2 * HH));
        x0.x *= g0.x; x0.y *= g0.y; x0.z *= g0.z; x0.w *= g0.w;
      }
      a0.x += v0 * x0.x; a0.y += v0 * x0.y; a0.z += v0 * x0.z; a0.w += v0 * x0.w;
    }
    float4 o;
    o.x = a0.x + a1.x; o.y = a0.y + a1.y; o.z = a0.z + a1.z; o.w = a0.w + a1.w;
    *(float4*)x1p = o;
    if (s == 0) {
      float4 x = *(const float4*)(sb + (size_t)r * HH);
      if (MODE) {
        float4 g = *(const float4*)(gb + (size_t)r * (2 * HH));
        x.x *= g.x; x.y *= g.y; x.z *= g.z; x.w *= g.w;
      }
      *(float4*)x0p = x;
    }
  } else if (fn == HH) {
    if (MODE) return;  // xi columns persist from MODE 0
    const float* xb = xi + (size_t)b * NN * INDIM;
    float p0 = 0.f, p1 = 0.f, q0 = 0.f, q1 = 0.f;
    int e = start;
    for (; e + 1 < end; e += 2) {
      int c0 = cs[e], c1 = cs[e + 1];
      float v0 = vs[e], v1 = vs[e + 1];
      p0 += v0 * xb[(size_t)c0 * INDIM];
      q0 += v0 * xb[(size_t)c0 * INDIM + 1];
      p1 += v1 * xb[(size_t)c1 * INDIM];
      q1 += v1 * xb[(size_t)c1 * INDIM + 1];
    }
    if (e < end) {
      int c0 = cs[e];
      float v0 = vs[e];
      p0 += v0 * xb[(size_t)c0 * INDIM];
      q0 += v0 * xb[(size_t)c0 * INDIM + 1];
    }
    float4 o = {p0 + p1, q0 + q1, 0.f, 0.f};
    *(float4*)x1p = o;
    if (s == 0) {
      float4 x = {xb[(size_t)r * INDIM], xb[(size_t)r * INDIM + 1], 0.f, 0.f};
      *(float4*)x0p = x;
    }
  } else {
    if (MODE) return;  // pads persist from MODE 0
    float4 z = {0.f, 0.f, 0.f, 0.f};
    *(float4*)x1p = z;
    if (s == 0) *(float4*)x0p = z;
  }
}

// ---------------- hop2: x2 = 2*A@x1 - x0 (columnwise independent) ----------------
// LAYER 0: CP=768, state cols f<64, xi 64..65, pads >=66
// LAYER 1: CP=1024, xi cols f<64, state f>=64
// MODE==1 recomputes only state columns (others persist from MODE 0)
template <int LAYER, int MODE>
__global__ __launch_bounds__(256) void spmm2_kernel(
    const int* __restrict__ row_start, const int* __restrict__ cols,
    const float* __restrict__ vals, float* __restrict__ mats) {
  constexpr int FPP = (LAYER == 0) ? FP0 : FP1;
  constexpr int CPX = BB * FPP;
  const int tid = threadIdx.x;
  int c4, fn;
  if (LAYER == 0) {
    constexpr int SLOTS = FP0 / 4;
    if (tid >= BB * SLOTS) return;
    const int b = tid / SLOTS;
    fn = (tid - b * SLOTS) * 4;
    c4 = b * FP0 + fn;
    if (MODE == 1 && fn >= HH) return;  // xi+pads persist
  } else {
    c4 = tid * 4;
    fn = c4 & (FP1 - 1);
    if (MODE == 1 && fn < HH) return;   // xi cols persist
  }
  const int r = blockIdx.x, s = blockIdx.y;
  const size_t NC = (size_t)NN * CPX;
  float* xout = mats + (size_t)(2 + 2 * s) * NC + (size_t)r * CPX + c4;

  if (LAYER == 0 && MODE == 0 && fn >= HH + 4) {  // pure-pad slots (fn>=68)
    float4 z = {0.f, 0.f, 0.f, 0.f};
    *(float4*)xout = z;
    return;
  }

  const float* xin = mats + (size_t)(1 + 2 * s) * NC + c4;
  const int* rs = row_start + s * (NN + 1);
  const int* cs = cols + s * NNZE;
  const float* vs = vals + s * NNZE;
  const int start = rs[r], end = rs[r + 1];

  float4 a0 = {0.f, 0.f, 0.f, 0.f}, a1 = {0.f, 0.f, 0.f, 0.f};
  int e = start;
  for (; e + 1 < end; e += 2) {
    int c0 = cs[e], c1 = cs[e + 1];
    float v0 = vs[e], v1 = vs[e + 1];
    float4 x0 = *(const float4*)(xin + (size_t)c0 * CPX);
    float4 x1 = *(const float4*)(xin + (size_t)c1 * CPX);
    a0.x += v0 * x0.x; a0.y += v0 * x0.y; a0.z += v0 * x0.z; a0.w += v0 * x0.w;
    a1.x += v1 * x1.x; a1.y += v1 * x1.y; a1.z += v1 * x1.z; a1.w += v1 * x1.w;
  }
  if (e < end) {
    int c0 = cs[e];
    float v0 = vs[e];
    float4 x0 = *(const float4*)(xin + (size_t)c0 * CPX);
    a0.x += v0 * x0.x; a0.y += v0 * x0.y; a0.z += v0 * x0.z; a0.w += v0 * x0.w;
  }
  float4 p = *(const float4*)(mats + (size_t)r * CPX + c4);  // x0 row
  float4 o;
  o.x = 2.f * (a0.x + a1.x) - p.x;
  o.y = 2.f * (a0.y + a1.y) - p.y;
  o.z = 2.f * (a0.z + a1.z) - p.z;
  o.w = 2.f * (a0.w + a1.w) - p.w;
  *(float4*)xout = o;
}

// ---------------- MFMA bf16x3 GEMM with fused epilogue ----------------
// out[bn][j] = sum_k A[bn][k] * W[k][j]; A = mats fp32 split to bf16 hi/lo at staging,
// W = precomputed transposed bf16 planes. A*W ~= Ah*Wh + Ah*Wl + Al*Wh (fp32 MFMA accum).
// MODE 0: gatesOut = sigmoid(.+bias)  (JJ=128, grid.y=2)
// MODE 1: c=tanh(.+bias); u=gatesIn[bn][H+jj]; ns=u*s+(1-u)*c -> state, outT (JJ=64)
template <int MODE, int FPP, int JJ>
__global__ __launch_bounds__(256) void gemm_mfma_kernel(
    const float* __restrict__ mats, const unsigned short* __restrict__ WTh,
    const unsigned short* __restrict__ WTl, const float* __restrict__ bias,
    float* __restrict__ gatesOut, const float* __restrict__ gatesIn,
    float* __restrict__ state, float* __restrict__ outT) {
  constexpr int KT = 32;
  constexpr int LDR = 56;
  constexpr int CP = BB * FPP;
  constexpr int KTOT = MM * FPP;
  constexpr int NPH = KTOT / KT;

  __shared__ unsigned short As[2][2][64][LDR];
  __shared__ unsigned short Ws[2][2][64][LDR];

  const int tid = threadIdx.x;
  const int lane = tid & 63;
  const int wid = tid >> 6;
  const int wr = wid >> 1, wc = wid & 1;
  const int lr = lane & 15, g = lane >> 4;

  const int bn0 = blockIdx.x * 64;
  const int jb0 = blockIdx.y * 64;
  const int nB = bn0 >> 10;
  const int n0 = bn0 & (NN - 1);

  const int srow = tid >> 2;
  const int scol = (tid & 3) * 8;

  float av[8];
  uint4 wh, wl;

  auto gload = [&](int ph) {
    const int m = (ph * KT) / FPP;
    const int f0 = (ph * KT) - m * FPP;
    const float* ab =
        mats + (size_t)m * NN * CP + (size_t)(n0 + srow) * CP + nB * FPP + f0 + scol;
    *(float4*)&av[0] = *(const float4*)ab;
    *(float4*)&av[4] = *(const float4*)(ab + 4);
    const size_t woff = (size_t)(jb0 + srow) * KTOT + ph * KT + scol;
    wh = *(const uint4*)(WTh + woff);
    wl = *(const uint4*)(WTl + woff);
  };
  auto stos = [&](int buf) {
    unsigned short h8[8], l8[8];
#pragma unroll
    for (int q = 0; q < 8; ++q) {
      float x = av[q];
      unsigned u = __float_as_uint(x);
      h8[q] = (unsigned short)(u >> 16);
      float hf = __uint_as_float(u & 0xFFFF0000u);
      l8[q] = (unsigned short)(__float_as_uint(x - hf) >> 16);
    }
    *(uint4*)&As[buf][0][srow][scol] = *(uint4*)h8;
    *(uint4*)&As[buf][1][srow][scol] = *(uint4*)l8;
    *(uint4*)&Ws[buf][0][srow][scol] = wh;
    *(uint4*)&Ws[buf][1][srow][scol] = wl;
  };

  f32x4 acc[2][2] = {};

  auto domfma = [&](int cur) {
    bf16x8 a[2][2], b[2][2];
#pragma unroll
    for (int tr = 0; tr < 2; ++tr)
#pragma unroll
      for (int pl = 0; pl < 2; ++pl)
        a[tr][pl] = *(const bf16x8*)&As[cur][pl][wr * 32 + tr * 16 + lr][g * 8];
#pragma unroll
    for (int tc = 0; tc < 2; ++tc)
#pragma unroll
      for (int pl = 0; pl < 2; ++pl)
        b[tc][pl] = *(const bf16x8*)&Ws[cur][pl][wc * 32 + tc * 16 + lr][g * 8];
#pragma unroll
    for (int tr = 0; tr < 2; ++tr)
#pragma unroll
      for (int tc = 0; tc < 2; ++tc) {
        acc[tr][tc] =
            __builtin_amdgcn_mfma_f32_16x16x32_bf16(a[tr][0], b[tc][0], acc[tr][tc], 0, 0, 0);
        acc[tr][tc] =
            __builtin_amdgcn_mfma_f32_16x16x32_bf16(a[tr][0], b[tc][1], acc[tr][tc], 0, 0, 0);
        acc[tr][tc] =
            __builtin_amdgcn_mfma_f32_16x16x32_bf16(a[tr][1], b[tc][0], acc[tr][tc], 0, 0, 0);
      }
  };

  gload(0);
  stos(0);
  __syncthreads();

  for (int ph = 0; ph < NPH; ++ph) {
    const int cur = ph & 1;
    if (ph + 1 < NPH) gload(ph + 1);
    domfma(cur);
    if (ph + 1 < NPH) {
      stos(cur ^ 1);
      __syncthreads();
    }
  }

  // epilogue: C/D frag mapping col = lane&15, row = (lane>>4)*4 + reg
#pragma unroll
  for (int tr = 0; tr < 2; ++tr)
#pragma unroll
    for (int tc = 0; tc < 2; ++tc) {
      const int jj = jb0 + wc * 32 + tc * 16 + lr;
      const float bs = bias[jj];
#pragma unroll
      for (int q = 0; q < 4; ++q) {
        const int bn = bn0 + wr * 32 + tr * 16 + g * 4 + q;
        float v = acc[tr][tc][q] + bs;
        if (MODE == 0) {
          gatesOut[(size_t)bn * (2 * HH) + jj] = 1.f / (1.f + expf(-v));
        } else {
          const int n = bn & (NN - 1);
          const int b = bn >> 10;
          float c = tanhf(v);
          float u = gatesIn[(size_t)bn * (2 * HH) + HH + jj];
          size_t si = (size_t)b * (NN * HH) + (size_t)n * HH + jj;
          float s = state[si];
          float ns = u * s + (1.f - u) * c;
          state[si] = ns;
          outT[si] = ns;
        }
      }
    }
}

// ---------------- host orchestration ----------------
extern "C" void kernel_launch(void* const* d_in, const int* in_sizes, int n_in, void* d_out,
                              int out_size, void* d_ws, size_t ws_size, hipStream_t stream) {
  const float* inputs = (const float*)d_in[0];
  const float* init_h = (const float*)d_in[1];
  const int* sup_rows = (const int*)d_in[2];
  const int* sup_cols = (const int*)d_in[3];
  const float* sup_vals = (const float*)d_in[4];
  const float* Wg[2] = {(const float*)d_in[5], (const float*)d_in[9]};
  const float* bg[2] = {(const float*)d_in[6], (const float*)d_in[10]};
  const float* Wc[2] = {(const float*)d_in[7], (const float*)d_in[11]};
  const float* bc[2] = {(const float*)d_in[8], (const float*)d_in[12]};

  float* out_h = (float*)d_out;                  // [L][B*N*H] final hidden states
  float* out_cur = out_h + (size_t)LL * BNH;     // [T][B*N*H] layer-1 outputs

  char* p = (char*)d_ws;
  auto alloc = [&](size_t bytes) -> void* {
    void* r = (void*)p;
    p += (bytes + 255) & ~(size_t)255;
    return r;
  };
  int* colsS = (int*)alloc(2 * NNZE * sizeof(int));
  float* valsS = (float*)alloc(2 * NNZE * sizeof(float));
  int* row_start = (int*)alloc(2 * (NN + 1) * sizeof(int));
  int* cursor = (int*)alloc(2 * NN * sizeof(int));
  int* counts = (int*)alloc(2 * NN * sizeof(int));
  const int K0 = MM * FP0, K1 = MM * FP1;  // 480, 640
  unsigned short* WgTh[2];
  unsigned short* WgTl[2];
  unsigned short* WcTh[2];
  unsigned short* WcTl[2];
  WgTh[0] = (unsigned short*)alloc((size_t)128 * K0 * 2);
  WgTl[0] = (unsigned short*)alloc((size_t)128 * K0 * 2);
  WcTh[0] = (unsigned short*)alloc((size_t)64 * K0 * 2);
  WcTl[0] = (unsigned short*)alloc((size_t)64 * K0 * 2);
  WgTh[1] = (unsigned short*)alloc((size_t)128 * K1 * 2);
  WgTl[1] = (unsigned short*)alloc((size_t)128 * K1 * 2);
  WcTh[1] = (unsigned short*)alloc((size_t)64 * K1 * 2);
  WcTl[1] = (unsigned short*)alloc((size_t)64 * K1 * 2);
  float* mats = (float*)alloc((size_t)MM * NN * CP1 * sizeof(float));     // 20 MB
  float* gatesBuf = (float*)alloc((size_t)BB * NN * 128 * sizeof(float)); // 4 MB
  float* x01 = (float*)alloc(BNH * sizeof(float));                        // 2 MB

  // --- CSR build ---
  zero_int_kernel<<<(2 * NN + 255) / 256, 256, 0, stream>>>(counts, 2 * NN);
  csr_count_kernel<<<(2 * NNZE + 255) / 256, 256, 0, stream>>>(sup_rows, counts);
  csr_scan_kernel<<<2, NN, 0, stream>>>(counts, row_start, cursor);
  csr_scatter_kernel<<<(2 * NNZE + 255) / 256, 256, 0, stream>>>(sup_rows, sup_cols, sup_vals,
                                                                 cursor, colsS, valsS);
  // --- permute + transpose + bf16-split weights (layer0 reordered: state-first) ---
  permwT_kernel<<<(128 * K0 + 255) / 256, 256, 0, stream>>>(Wg[0], WgTh[0], WgTl[0], 66, FP0, 128, 1);
  permwT_kernel<<<(64 * K0 + 255) / 256, 256, 0, stream>>>(Wc[0], WcTh[0], WcTl[0], 66, FP0, 64, 1);
  permwT_kernel<<<(128 * K1 + 255) / 256, 256, 0, stream>>>(Wg[1], WgTh[1], WgTl[1], 128, FP1, 128, 0);
  permwT_kernel<<<(64 * K1 + 255) / 256, 256, 0, stream>>>(Wc[1], WcTh[1], WcTl[1], 128, FP1, 64, 0);
  // --- init states (live in d_out) ---
  copy_kernel<<<((int)(LL * BNH) + 255) / 256, 256, 0, stream>>>(init_h, out_h, (int)(LL * BNH));

  for (int t = 0; t < TT; ++t) {
    // ---- layer 0 ----
    {
      float* state = out_h;
      const float* xi = inputs + (size_t)t * BB * NN * INDIM;
      float* outT = x01;
      spmm1_l0_kernel<0><<<dim3(NN, 2), 256, 0, stream>>>(row_start, colsS, valsS, xi, state,
                                                          nullptr, mats);
      spmm2_kernel<0, 0><<<dim3(NN, 2), 256, 0, stream>>>(row_start, colsS, valsS, mats);
      gemm_mfma_kernel<0, FP0, 128><<<dim3(BB * NN / 64, 2), 256, 0, stream>>>(
          mats, WgTh[0], WgTl[0], bg[0], gatesBuf, nullptr, nullptr, nullptr);
      spmm1_l0_kernel<1><<<dim3(NN, 2), 256, 0, stream>>>(row_start, colsS, valsS, xi, state,
                                                          gatesBuf, mats);
      spmm2_kernel<0, 1><<<dim3(NN, 2), 256, 0, stream>>>(row_start, colsS, valsS, mats);
      gemm_mfma_kernel<1, FP0, 64><<<dim3(BB * NN / 64, 1), 256, 0, stream>>>(
          mats, WcTh[0], WcTl[0], bc[0], nullptr, gatesBuf, state, outT);
    }
    // ---- layer 1 ----
    {
      float* state = out_h + BNH;
      const float* xi = x01;
      float* outT = out_cur + (size_t)t * BNH;
      spmm1_l1_kernel<0><<<dim3(NN, 2), 256, 0, stream>>>(row_start, colsS, valsS, xi, state,
                                                          nullptr, mats);
      spmm2_kernel<1, 0><<<dim3(NN, 2), 256, 0, stream>>>(row_start, colsS, valsS, mats);
      gemm_mfma_kernel<0, FP1, 128><<<dim3(BB * NN / 64, 2), 256, 0, stream>>>(
          mats, WgTh[1], WgTl[1], bg[1], gatesBuf, nullptr, nullptr, nullptr);
      spmm1_l1_kernel<1><<<dim3(NN, 2), 256, 0, stream>>>(row_start, colsS, valsS, xi, state,
                                                          gatesBuf, mats);
      spmm2_kernel<1, 1><<<dim3(NN, 2), 256, 0, stream>>>(row_start, colsS, valsS, mats);
      gemm_mfma_kernel<1, FP1, 64><<<dim3(BB * NN / 64, 1), 256, 0, stream>>>(
          mats, WcTh[1], WcTl[1], bc[1], nullptr, gatesBuf, state, outT);
    }
  }
}

// Round 11
// 1877.263 us; speedup vs baseline: 2.6773x; 1.0851x over previous
//
#include <hip/hip_runtime.h>
#include <hip/hip_bf16.h>
#include <math.h>

// Problem constants (fixed by the reference)
#define NN 1024
#define HH 64
#define TT 12
#define BB 8
#define INDIM 2
#define LL 2
#define NNZE 16384
#define MM 5

// Padded per-mat feature dims. Layer-0 order: [state(64), xi(2), pad(30)]; layer-1: [xi(64), state(64)]
#define FP0 96
#define FP1 128
#define CP0 (BB * FP0)   // 768
#define CP1 (BB * FP1)   // 1024

static constexpr size_t BNH = (size_t)BB * NN * HH;  // 524288

typedef short bf16x8 __attribute__((ext_vector_type(8)));
typedef float f32x4 __attribute__((ext_vector_type(4)));

// fma4 as a FUNCTION, not a macro: a macro body `acc.x += v * x.x` breaks because the
// `x` token after `.` is also substituted (round-10 compile failure).
__device__ __forceinline__ void fma4(float4& acc, float v, const float4& p) {
  acc.x += v * p.x;
  acc.y += v * p.y;
  acc.z += v * p.z;
  acc.w += v * p.w;
}
__device__ __forceinline__ void mul4(float4& a, const float4& g) {
  a.x *= g.x; a.y *= g.y; a.z *= g.z; a.w *= g.w;
}

// ---------------- small utility kernels ----------------
__global__ void zero_int_kernel(int* p, int n) {
  int i = blockIdx.x * blockDim.x + threadIdx.x;
  if (i < n) p[i] = 0;
}

__global__ void copy_kernel(const float* __restrict__ src, float* __restrict__ dst, int n) {
  int i = blockIdx.x * blockDim.x + threadIdx.x;
  if (i < n) dst[i] = src[i];
}

// ---------------- CSR build ----------------
__global__ void csr_count_kernel(const int* __restrict__ rows, int* __restrict__ counts) {
  int i = blockIdx.x * blockDim.x + threadIdx.x;
  if (i < 2 * NNZE) {
    int s = i / NNZE;
    atomicAdd(&counts[s * NN + rows[i]], 1);
  }
}

__global__ void csr_scan_kernel(const int* __restrict__ counts, int* __restrict__ row_start,
                                int* __restrict__ cursor) {
  __shared__ int bufA[NN];
  __shared__ int bufB[NN];
  int s = blockIdx.x;
  int t = threadIdx.x;
  bufA[t] = counts[s * NN + t];
  __syncthreads();
  int* src = bufA;
  int* dst = bufB;
  for (int off = 1; off < NN; off <<= 1) {
    dst[t] = src[t] + (t >= off ? src[t - off] : 0);
    __syncthreads();
    int* tmp = src; src = dst; dst = tmp;
  }
  row_start[s * (NN + 1) + t + 1] = src[t];
  cursor[s * NN + t] = (t == 0) ? 0 : src[t - 1];
  if (t == 0) row_start[s * (NN + 1)] = 0;
}

__global__ void csr_scatter_kernel(const int* __restrict__ rows, const int* __restrict__ colsIn,
                                   const float* __restrict__ valsIn, int* __restrict__ cursor,
                                   int* __restrict__ colsOut, float* __restrict__ valsOut) {
  int i = blockIdx.x * blockDim.x + threadIdx.x;
  if (i < 2 * NNZE) {
    int s = i / NNZE;
    int r = rows[i];
    int pos = atomicAdd(&cursor[s * NN + r], 1);
    colsOut[s * NNZE + pos] = colsIn[i];
    valsOut[s * NNZE + pos] = valsIn[i];
  }
}

// ---------------- weight permute + transpose + bf16 hi/lo split ----------------
__global__ void permwT_kernel(const float* __restrict__ W, unsigned short* __restrict__ WTh,
                              unsigned short* __restrict__ WTl, int F, int Fp, int J, int reord) {
  int Ktot = MM * Fp;
  int total = J * Ktot;
  for (int idx = blockIdx.x * blockDim.x + threadIdx.x; idx < total;
       idx += gridDim.x * blockDim.x) {
    int k = idx % Ktot;
    int j = idx / Ktot;
    int m = k / Fp;
    int fn = k - m * Fp;
    int fo;
    if (reord) {
      fo = (fn < HH) ? fn + INDIM : (fn < HH + INDIM ? fn - HH : -1);
    } else {
      fo = (fn < F) ? fn : -1;
    }
    float x = (fo >= 0) ? W[(size_t)(fo * MM + m) * J + j] : 0.f;
    unsigned u = __float_as_uint(x);
    WTh[idx] = (unsigned short)(u >> 16);
    float hf = __uint_as_float(u & 0xFFFF0000u);
    WTl[idx] = (unsigned short)(__float_as_uint(x - hf) >> 16);
  }
}

// ---------------- spmm1 layer1, gates pass (full width) ----------------
__global__ __launch_bounds__(256) void spmm1_l1_kernel(
    const int* __restrict__ row_start, const int* __restrict__ cols,
    const float* __restrict__ vals, const float* __restrict__ xi,   // [B][N][64]
    const float* __restrict__ state,                                 // [B][N][64]
    float* __restrict__ mats) {
  const int r = blockIdx.x, s = blockIdx.y, tid = threadIdx.x;
  const int b = tid >> 5;
  const int f = (tid & 31) * 4;
  const bool isX = (f < HH);
  const float* src = isX ? xi : state;
  const float* sb = src + (size_t)b * NN * HH + (isX ? f : f - HH);

  const int* rs = row_start + s * (NN + 1);
  const int* cs = cols + s * NNZE;
  const float* vs = vals + s * NNZE;
  const int start = rs[r], end = rs[r + 1];

  float4 a0 = {0, 0, 0, 0}, a1 = {0, 0, 0, 0}, a2 = {0, 0, 0, 0}, a3 = {0, 0, 0, 0};
  int e = start;
  for (; e + 3 < end; e += 4) {
    int c0 = cs[e], c1 = cs[e + 1], c2 = cs[e + 2], c3 = cs[e + 3];
    float v0 = vs[e], v1 = vs[e + 1], v2 = vs[e + 2], v3 = vs[e + 3];
    float4 x0 = *(const float4*)(sb + (size_t)c0 * HH);
    float4 x1 = *(const float4*)(sb + (size_t)c1 * HH);
    float4 x2 = *(const float4*)(sb + (size_t)c2 * HH);
    float4 x3 = *(const float4*)(sb + (size_t)c3 * HH);
    fma4(a0, v0, x0); fma4(a1, v1, x1); fma4(a2, v2, x2); fma4(a3, v3, x3);
  }
  for (; e < end; ++e) {
    int c0 = cs[e];
    float v0 = vs[e];
    float4 x0 = *(const float4*)(sb + (size_t)c0 * HH);
    fma4(a0, v0, x0);
  }
  float4 o;
  o.x = (a0.x + a1.x) + (a2.x + a3.x);
  o.y = (a0.y + a1.y) + (a2.y + a3.y);
  o.z = (a0.z + a1.z) + (a2.z + a3.z);
  o.w = (a0.w + a1.w) + (a2.w + a3.w);
  *(float4*)(mats + (size_t)(1 + 2 * s) * (NN * CP1) + (size_t)r * CP1 + tid * 4) = o;

  if (s == 0) {  // materialize x0 row r
    *(float4*)(mats + (size_t)r * CP1 + tid * 4) = *(const float4*)(sb + (size_t)r * HH);
  }
}

// ---------------- spmm1 layer0, gates pass (state-first layout) ----------------
__global__ __launch_bounds__(256) void spmm1_l0_kernel(
    const int* __restrict__ row_start, const int* __restrict__ cols,
    const float* __restrict__ vals, const float* __restrict__ xi,   // [B][N][2]
    const float* __restrict__ state,                                 // [B][N][64]
    float* __restrict__ mats) {
  const int tid = threadIdx.x;
  constexpr int SLOTS = FP0 / 4;  // 24
  if (tid >= BB * SLOTS) return;
  const int r = blockIdx.x, s = blockIdx.y;
  const int b = tid / SLOTS;
  const int fn = (tid - b * SLOTS) * 4;
  const int c4 = b * FP0 + fn;

  float* x1p = mats + (size_t)(1 + 2 * s) * (NN * CP0) + (size_t)r * CP0 + c4;
  float* x0p = mats + (size_t)r * CP0 + c4;

  const int* rs = row_start + s * (NN + 1);
  const int* cs = cols + s * NNZE;
  const float* vs = vals + s * NNZE;
  const int start = rs[r], end = rs[r + 1];

  if (fn < HH) {
    const float* sb = state + (size_t)b * NN * HH + fn;
    float4 a0 = {0, 0, 0, 0}, a1 = {0, 0, 0, 0}, a2 = {0, 0, 0, 0}, a3 = {0, 0, 0, 0};
    int e = start;
    for (; e + 3 < end; e += 4) {
      int c0 = cs[e], c1 = cs[e + 1], c2 = cs[e + 2], c3 = cs[e + 3];
      float v0 = vs[e], v1 = vs[e + 1], v2 = vs[e + 2], v3 = vs[e + 3];
      float4 x0 = *(const float4*)(sb + (size_t)c0 * HH);
      float4 x1 = *(const float4*)(sb + (size_t)c1 * HH);
      float4 x2 = *(const float4*)(sb + (size_t)c2 * HH);
      float4 x3 = *(const float4*)(sb + (size_t)c3 * HH);
      fma4(a0, v0, x0); fma4(a1, v1, x1); fma4(a2, v2, x2); fma4(a3, v3, x3);
    }
    for (; e < end; ++e) {
      int c0 = cs[e];
      float v0 = vs[e];
      float4 x0 = *(const float4*)(sb + (size_t)c0 * HH);
      fma4(a0, v0, x0);
    }
    float4 o;
    o.x = (a0.x + a1.x) + (a2.x + a3.x);
    o.y = (a0.y + a1.y) + (a2.y + a3.y);
    o.z = (a0.z + a1.z) + (a2.z + a3.z);
    o.w = (a0.w + a1.w) + (a2.w + a3.w);
    *(float4*)x1p = o;
    if (s == 0) *(float4*)x0p = *(const float4*)(sb + (size_t)r * HH);
  } else if (fn == HH) {
    const float* xb = xi + (size_t)b * NN * INDIM;
    float p0 = 0.f, p1 = 0.f, q0 = 0.f, q1 = 0.f;
    int e = start;
    for (; e + 1 < end; e += 2) {
      int c0 = cs[e], c1 = cs[e + 1];
      float v0 = vs[e], v1 = vs[e + 1];
      p0 += v0 * xb[(size_t)c0 * INDIM];
      q0 += v0 * xb[(size_t)c0 * INDIM + 1];
      p1 += v1 * xb[(size_t)c1 * INDIM];
      q1 += v1 * xb[(size_t)c1 * INDIM + 1];
    }
    if (e < end) {
      int c0 = cs[e];
      float v0 = vs[e];
      p0 += v0 * xb[(size_t)c0 * INDIM];
      q0 += v0 * xb[(size_t)c0 * INDIM + 1];
    }
    float4 o = {p0 + p1, q0 + q1, 0.f, 0.f};
    *(float4*)x1p = o;
    if (s == 0) {
      float4 x = {xb[(size_t)r * INDIM], xb[(size_t)r * INDIM + 1], 0.f, 0.f};
      *(float4*)x0p = x;
    }
  } else {
    float4 z = {0, 0, 0, 0};
    *(float4*)x1p = z;
    if (s == 0) *(float4*)x0p = z;
  }
}

// ---------------- spmm1 candidate pass: state cols only, packed (both layers) ----------------
// 128 slots/row (8 b x 16 f-quads), 2 rows per 256-thread block. grid (NN/2, 2).
// Writes r*state diffusion into mats[1+2s] state cols; s==0 also writes x0 state cols (r*state).
template <int LAYER>
__global__ __launch_bounds__(256) void spmm1_state_kernel(
    const int* __restrict__ row_start, const int* __restrict__ cols,
    const float* __restrict__ vals, const float* __restrict__ state,
    const float* __restrict__ gates, float* __restrict__ mats) {
  constexpr int FPP = (LAYER == 0) ? FP0 : FP1;
  constexpr int CP = BB * FPP;
  constexpr int BASE = (LAYER == 0) ? 0 : HH;  // state col offset within a batch's features
  const int tid = threadIdx.x;
  const int r = blockIdx.x * 2 + (tid >> 7);
  const int slot = tid & 127;
  const int b = slot >> 4;
  const int fi = (slot & 15) * 4;
  const int s = blockIdx.y;

  const float* sb = state + (size_t)b * NN * HH + fi;
  const float* gb = gates + (size_t)b * NN * (2 * HH) + fi;

  const int* rs = row_start + s * (NN + 1);
  const int* cs = cols + s * NNZE;
  const float* vs = vals + s * NNZE;
  const int start = rs[r], end = rs[r + 1];

  float4 a0 = {0, 0, 0, 0}, a1 = {0, 0, 0, 0}, a2 = {0, 0, 0, 0}, a3 = {0, 0, 0, 0};
  int e = start;
  for (; e + 3 < end; e += 4) {
    int c0 = cs[e], c1 = cs[e + 1], c2 = cs[e + 2], c3 = cs[e + 3];
    float v0 = vs[e], v1 = vs[e + 1], v2 = vs[e + 2], v3 = vs[e + 3];
    float4 x0 = *(const float4*)(sb + (size_t)c0 * HH);
    float4 g0 = *(const float4*)(gb + (size_t)c0 * (2 * HH));
    float4 x1 = *(const float4*)(sb + (size_t)c1 * HH);
    float4 g1 = *(const float4*)(gb + (size_t)c1 * (2 * HH));
    float4 x2 = *(const float4*)(sb + (size_t)c2 * HH);
    float4 g2 = *(const float4*)(gb + (size_t)c2 * (2 * HH));
    float4 x3 = *(const float4*)(sb + (size_t)c3 * HH);
    float4 g3 = *(const float4*)(gb + (size_t)c3 * (2 * HH));
    mul4(x0, g0); mul4(x1, g1); mul4(x2, g2); mul4(x3, g3);
    fma4(a0, v0, x0); fma4(a1, v1, x1); fma4(a2, v2, x2); fma4(a3, v3, x3);
  }
  for (; e < end; ++e) {
    int c0 = cs[e];
    float v0 = vs[e];
    float4 x0 = *(const float4*)(sb + (size_t)c0 * HH);
    float4 g0 = *(const float4*)(gb + (size_t)c0 * (2 * HH));
    mul4(x0, g0);
    fma4(a0, v0, x0);
  }
  float4 o;
  o.x = (a0.x + a1.x) + (a2.x + a3.x);
  o.y = (a0.y + a1.y) + (a2.y + a3.y);
  o.z = (a0.z + a1.z) + (a2.z + a3.z);
  o.w = (a0.w + a1.w) + (a2.w + a3.w);
  const int c4 = b * FPP + BASE + fi;
  *(float4*)(mats + (size_t)(1 + 2 * s) * (NN * CP) + (size_t)r * CP + c4) = o;

  if (s == 0) {  // x0 state cols = r*state (row-local)
    float4 x = *(const float4*)(sb + (size_t)r * HH);
    float4 g = *(const float4*)(gb + (size_t)r * (2 * HH));
    mul4(x, g);
    *(float4*)(mats + (size_t)r * CP + c4) = x;
  }
}

// ---------------- spmm2 gates pass (full width): x2 = 2*A@x1 - x0 ----------------
template <int LAYER>
__global__ __launch_bounds__(256) void spmm2_kernel(
    const int* __restrict__ row_start, const int* __restrict__ cols,
    const float* __restrict__ vals, float* __restrict__ mats) {
  constexpr int FPP = (LAYER == 0) ? FP0 : FP1;
  constexpr int CPX = BB * FPP;
  const int tid = threadIdx.x;
  int c4, fn;
  if (LAYER == 0) {
    constexpr int SLOTS = FP0 / 4;
    if (tid >= BB * SLOTS) return;
    const int b = tid / SLOTS;
    fn = (tid - b * SLOTS) * 4;
    c4 = b * FP0 + fn;
  } else {
    c4 = tid * 4;
    fn = c4 & (FP1 - 1);
  }
  const int r = blockIdx.x, s = blockIdx.y;
  const size_t NC = (size_t)NN * CPX;
  float* xout = mats + (size_t)(2 + 2 * s) * NC + (size_t)r * CPX + c4;

  if (LAYER == 0 && fn >= HH + 4) {  // pure-pad slots
    float4 z = {0, 0, 0, 0};
    *(float4*)xout = z;
    return;
  }

  const float* xin = mats + (size_t)(1 + 2 * s) * NC + c4;
  const int* rs = row_start + s * (NN + 1);
  const int* cs = cols + s * NNZE;
  const float* vs = vals + s * NNZE;
  const int start = rs[r], end = rs[r + 1];

  float4 a0 = {0, 0, 0, 0}, a1 = {0, 0, 0, 0}, a2 = {0, 0, 0, 0}, a3 = {0, 0, 0, 0};
  int e = start;
  for (; e + 3 < end; e += 4) {
    int c0 = cs[e], c1 = cs[e + 1], c2 = cs[e + 2], c3 = cs[e + 3];
    float v0 = vs[e], v1 = vs[e + 1], v2 = vs[e + 2], v3 = vs[e + 3];
    float4 x0 = *(const float4*)(xin + (size_t)c0 * CPX);
    float4 x1 = *(const float4*)(xin + (size_t)c1 * CPX);
    float4 x2 = *(const float4*)(xin + (size_t)c2 * CPX);
    float4 x3 = *(const float4*)(xin + (size_t)c3 * CPX);
    fma4(a0, v0, x0); fma4(a1, v1, x1); fma4(a2, v2, x2); fma4(a3, v3, x3);
  }
  for (; e < end; ++e) {
    int c0 = cs[e];
    float v0 = vs[e];
    float4 x0 = *(const float4*)(xin + (size_t)c0 * CPX);
    fma4(a0, v0, x0);
  }
  float4 p = *(const float4*)(mats + (size_t)r * CPX + c4);
  float4 o;
  o.x = 2.f * ((a0.x + a1.x) + (a2.x + a3.x)) - p.x;
  o.y = 2.f * ((a0.y + a1.y) + (a2.y + a3.y)) - p.y;
  o.z = 2.f * ((a0.z + a1.z) + (a2.z + a3.z)) - p.z;
  o.w = 2.f * ((a0.w + a1.w) + (a2.w + a3.w)) - p.w;
  *(float4*)xout = o;
}

// ---------------- spmm2 candidate pass: state cols only, packed ----------------
template <int LAYER>
__global__ __launch_bounds__(256) void spmm2_state_kernel(
    const int* __restrict__ row_start, const int* __restrict__ cols,
    const float* __restrict__ vals, float* __restrict__ mats) {
  constexpr int FPP = (LAYER == 0) ? FP0 : FP1;
  constexpr int CP = BB * FPP;
  constexpr int BASE = (LAYER == 0) ? 0 : HH;
  const int tid = threadIdx.x;
  const int r = blockIdx.x * 2 + (tid >> 7);
  const int slot = tid & 127;
  const int b = slot >> 4;
  const int fi = (slot & 15) * 4;
  const int s = blockIdx.y;
  const int c4 = b * FPP + BASE + fi;
  const size_t NC = (size_t)NN * CP;

  const float* xin = mats + (size_t)(1 + 2 * s) * NC + c4;
  const int* rs = row_start + s * (NN + 1);
  const int* cs = cols + s * NNZE;
  const float* vs = vals + s * NNZE;
  const int start = rs[r], end = rs[r + 1];

  float4 a0 = {0, 0, 0, 0}, a1 = {0, 0, 0, 0}, a2 = {0, 0, 0, 0}, a3 = {0, 0, 0, 0};
  int e = start;
  for (; e + 3 < end; e += 4) {
    int c0 = cs[e], c1 = cs[e + 1], c2 = cs[e + 2], c3 = cs[e + 3];
    float v0 = vs[e], v1 = vs[e + 1], v2 = vs[e + 2], v3 = vs[e + 3];
    float4 x0 = *(const float4*)(xin + (size_t)c0 * CP);
    float4 x1 = *(const float4*)(xin + (size_t)c1 * CP);
    float4 x2 = *(const float4*)(xin + (size_t)c2 * CP);
    float4 x3 = *(const float4*)(xin + (size_t)c3 * CP);
    fma4(a0, v0, x0); fma4(a1, v1, x1); fma4(a2, v2, x2); fma4(a3, v3, x3);
  }
  for (; e < end; ++e) {
    int c0 = cs[e];
    float v0 = vs[e];
    float4 x0 = *(const float4*)(xin + (size_t)c0 * CP);
    fma4(a0, v0, x0);
  }
  float4 p = *(const float4*)(mats + (size_t)r * CP + c4);  // x0 (r*state), from spmm1_state
  float4 o;
  o.x = 2.f * ((a0.x + a1.x) + (a2.x + a3.x)) - p.x;
  o.y = 2.f * ((a0.y + a1.y) + (a2.y + a3.y)) - p.y;
  o.z = 2.f * ((a0.z + a1.z) + (a2.z + a3.z)) - p.z;
  o.w = 2.f * ((a0.w + a1.w) + (a2.w + a3.w)) - p.w;
  *(float4*)(mats + (size_t)(2 + 2 * s) * NC + (size_t)r * CP + c4) = o;
}

// ---------------- MFMA bf16x3 GEMM with fused epilogue ----------------
// BM=64: 4 waves in 2x2, each 32x32 (acc 2x2). BM=32: 4 waves in 1x4, each 32x16 (acc 2x1).
template <int MODE, int BM, int FPP, int JJ>
__global__ __launch_bounds__(256) void gemm_mfma_kernel(
    const float* __restrict__ mats, const unsigned short* __restrict__ WTh,
    const unsigned short* __restrict__ WTl, const float* __restrict__ bias,
    float* __restrict__ gatesOut, const float* __restrict__ gatesIn,
    float* __restrict__ state, float* __restrict__ outT) {
  constexpr int KT = 32;
  constexpr int LDR = 56;
  constexpr int CP = BB * FPP;
  constexpr int KTOT = MM * FPP;
  constexpr int NPH = KTOT / KT;
  constexpr int WTC = (BM == 64) ? 2 : 1;

  __shared__ unsigned short As[2][2][BM][LDR];
  __shared__ unsigned short Ws[2][2][64][LDR];

  const int tid = threadIdx.x;
  const int lane = tid & 63;
  const int wid = tid >> 6;
  const int wr = (BM == 64) ? (wid >> 1) * 32 : 0;
  const int wc = (BM == 64) ? (wid & 1) * 32 : wid * 16;
  const int lr = lane & 15, g = lane >> 4;

  const int bn0 = blockIdx.x * BM;
  const int jb0 = blockIdx.y * 64;
  const int nB = bn0 >> 10;
  const int n0 = bn0 & (NN - 1);

  const int srow = tid >> 2;           // A row (BM=32: only tid<128 valid) / W j-row
  const int scol = (tid & 3) * 8;
  const bool doA = (BM == 64) || (tid < 128);

  float av[8];
  uint4 wh, wl;

  auto gload = [&](int ph) {
    const int m = (ph * KT) / FPP;
    const int f0 = (ph * KT) - m * FPP;
    if (doA) {
      const float* ab =
          mats + (size_t)m * NN * CP + (size_t)(n0 + srow) * CP + nB * FPP + f0 + scol;
      *(float4*)&av[0] = *(const float4*)ab;
      *(float4*)&av[4] = *(const float4*)(ab + 4);
    }
    const size_t woff = (size_t)(jb0 + srow) * KTOT + ph * KT + scol;
    wh = *(const uint4*)(WTh + woff);
    wl = *(const uint4*)(WTl + woff);
  };
  auto stos = [&](int buf) {
    if (doA) {
      unsigned short h8[8], l8[8];
#pragma unroll
      for (int q = 0; q < 8; ++q) {
        float x = av[q];
        unsigned u = __float_as_uint(x);
        h8[q] = (unsigned short)(u >> 16);
        float hf = __uint_as_float(u & 0xFFFF0000u);
        l8[q] = (unsigned short)(__float_as_uint(x - hf) >> 16);
      }
      *(uint4*)&As[buf][0][srow][scol] = *(uint4*)h8;
      *(uint4*)&As[buf][1][srow][scol] = *(uint4*)l8;
    }
    *(uint4*)&Ws[buf][0][srow][scol] = wh;
    *(uint4*)&Ws[buf][1][srow][scol] = wl;
  };

  f32x4 acc[2][WTC] = {};

  auto domfma = [&](int cur) {
    bf16x8 a[2][2], b[WTC][2];
#pragma unroll
    for (int tr = 0; tr < 2; ++tr)
#pragma unroll
      for (int pl = 0; pl < 2; ++pl)
        a[tr][pl] = *(const bf16x8*)&As[cur][pl][wr + tr * 16 + lr][g * 8];
#pragma unroll
    for (int tc = 0; tc < WTC; ++tc)
#pragma unroll
      for (int pl = 0; pl < 2; ++pl)
        b[tc][pl] = *(const bf16x8*)&Ws[cur][pl][wc + tc * 16 + lr][g * 8];
#pragma unroll
    for (int tr = 0; tr < 2; ++tr)
#pragma unroll
      for (int tc = 0; tc < WTC; ++tc) {
        acc[tr][tc] =
            __builtin_amdgcn_mfma_f32_16x16x32_bf16(a[tr][0], b[tc][0], acc[tr][tc], 0, 0, 0);
        acc[tr][tc] =
            __builtin_amdgcn_mfma_f32_16x16x32_bf16(a[tr][0], b[tc][1], acc[tr][tc], 0, 0, 0);
        acc[tr][tc] =
            __builtin_amdgcn_mfma_f32_16x16x32_bf16(a[tr][1], b[tc][0], acc[tr][tc], 0, 0, 0);
      }
  };

  gload(0);
  stos(0);
  __syncthreads();

  for (int ph = 0; ph < NPH; ++ph) {
    const int cur = ph & 1;
    if (ph + 1 < NPH) gload(ph + 1);
    domfma(cur);
    if (ph + 1 < NPH) {
      stos(cur ^ 1);
      __syncthreads();
    }
  }

  // epilogue: C/D frag mapping col = lane&15, row = (lane>>4)*4 + reg
#pragma unroll
  for (int tr = 0; tr < 2; ++tr)
#pragma unroll
    for (int tc = 0; tc < WTC; ++tc) {
      const int jj = jb0 + wc + tc * 16 + lr;
      const float bs = bias[jj];
#pragma unroll
      for (int q = 0; q < 4; ++q) {
        const int bn = bn0 + wr + tr * 16 + g * 4 + q;
        float v = acc[tr][tc][q] + bs;
        if (MODE == 0) {
          gatesOut[(size_t)bn * (2 * HH) + jj] = 1.f / (1.f + expf(-v));
        } else {
          const int n = bn & (NN - 1);
          const int b = bn >> 10;
          float c = tanhf(v);
          float u = gatesIn[(size_t)bn * (2 * HH) + HH + jj];
          size_t si = (size_t)b * (NN * HH) + (size_t)n * HH + jj;
          float s = state[si];
          float ns = u * s + (1.f - u) * c;
          state[si] = ns;
          outT[si] = ns;
        }
      }
    }
}

// ---------------- host orchestration ----------------
extern "C" void kernel_launch(void* const* d_in, const int* in_sizes, int n_in, void* d_out,
                              int out_size, void* d_ws, size_t ws_size, hipStream_t stream) {
  const float* inputs = (const float*)d_in[0];
  const float* init_h = (const float*)d_in[1];
  const int* sup_rows = (const int*)d_in[2];
  const int* sup_cols = (const int*)d_in[3];
  const float* sup_vals = (const float*)d_in[4];
  const float* Wg[2] = {(const float*)d_in[5], (const float*)d_in[9]};
  const float* bg[2] = {(const float*)d_in[6], (const float*)d_in[10]};
  const float* Wc[2] = {(const float*)d_in[7], (const float*)d_in[11]};
  const float* bc[2] = {(const float*)d_in[8], (const float*)d_in[12]};

  float* out_h = (float*)d_out;                  // [L][B*N*H] final hidden states
  float* out_cur = out_h + (size_t)LL * BNH;     // [T][B*N*H] layer-1 outputs

  char* p = (char*)d_ws;
  auto alloc = [&](size_t bytes) -> void* {
    void* r = (void*)p;
    p += (bytes + 255) & ~(size_t)255;
    return r;
  };
  int* colsS = (int*)alloc(2 * NNZE * sizeof(int));
  float* valsS = (float*)alloc(2 * NNZE * sizeof(float));
  int* row_start = (int*)alloc(2 * (NN + 1) * sizeof(int));
  int* cursor = (int*)alloc(2 * NN * sizeof(int));
  int* counts = (int*)alloc(2 * NN * sizeof(int));
  const int K0 = MM * FP0, K1 = MM * FP1;  // 480, 640
  unsigned short* WgTh[2];
  unsigned short* WgTl[2];
  unsigned short* WcTh[2];
  unsigned short* WcTl[2];
  WgTh[0] = (unsigned short*)alloc((size_t)128 * K0 * 2);
  WgTl[0] = (unsigned short*)alloc((size_t)128 * K0 * 2);
  WcTh[0] = (unsigned short*)alloc((size_t)64 * K0 * 2);
  WcTl[0] = (unsigned short*)alloc((size_t)64 * K0 * 2);
  WgTh[1] = (unsigned short*)alloc((size_t)128 * K1 * 2);
  WgTl[1] = (unsigned short*)alloc((size_t)128 * K1 * 2);
  WcTh[1] = (unsigned short*)alloc((size_t)64 * K1 * 2);
  WcTl[1] = (unsigned short*)alloc((size_t)64 * K1 * 2);
  float* mats = (float*)alloc((size_t)MM * NN * CP1 * sizeof(float));     // 20 MB
  float* gatesBuf = (float*)alloc((size_t)BB * NN * 128 * sizeof(float)); // 4 MB
  float* x01 = (float*)alloc(BNH * sizeof(float));                        // 2 MB

  // --- CSR build ---
  zero_int_kernel<<<(2 * NN + 255) / 256, 256, 0, stream>>>(counts, 2 * NN);
  csr_count_kernel<<<(2 * NNZE + 255) / 256, 256, 0, stream>>>(sup_rows, counts);
  csr_scan_kernel<<<2, NN, 0, stream>>>(counts, row_start, cursor);
  csr_scatter_kernel<<<(2 * NNZE + 255) / 256, 256, 0, stream>>>(sup_rows, sup_cols, sup_vals,
                                                                 cursor, colsS, valsS);
  // --- permute + transpose + bf16-split weights ---
  permwT_kernel<<<(128 * K0 + 255) / 256, 256, 0, stream>>>(Wg[0], WgTh[0], WgTl[0], 66, FP0, 128, 1);
  permwT_kernel<<<(64 * K0 + 255) / 256, 256, 0, stream>>>(Wc[0], WcTh[0], WcTl[0], 66, FP0, 64, 1);
  permwT_kernel<<<(128 * K1 + 255) / 256, 256, 0, stream>>>(Wg[1], WgTh[1], WgTl[1], 128, FP1, 128, 0);
  permwT_kernel<<<(64 * K1 + 255) / 256, 256, 0, stream>>>(Wc[1], WcTh[1], WcTl[1], 128, FP1, 64, 0);
  // --- init states (live in d_out) ---
  copy_kernel<<<((int)(LL * BNH) + 255) / 256, 256, 0, stream>>>(init_h, out_h, (int)(LL * BNH));

  for (int t = 0; t < TT; ++t) {
    // ---- layer 0 ----
    {
      float* state = out_h;
      const float* xi = inputs + (size_t)t * BB * NN * INDIM;
      float* outT = x01;
      spmm1_l0_kernel<<<dim3(NN, 2), 256, 0, stream>>>(row_start, colsS, valsS, xi, state, mats);
      spmm2_kernel<0><<<dim3(NN, 2), 256, 0, stream>>>(row_start, colsS, valsS, mats);
      gemm_mfma_kernel<0, 32, FP0, 128><<<dim3(BB * NN / 32, 2), 256, 0, stream>>>(
          mats, WgTh[0], WgTl[0], bg[0], gatesBuf, nullptr, nullptr, nullptr);
      spmm1_state_kernel<0><<<dim3(NN / 2, 2), 256, 0, stream>>>(row_start, colsS, valsS, state,
                                                                 gatesBuf, mats);
      spmm2_state_kernel<0><<<dim3(NN / 2, 2), 256, 0, stream>>>(row_start, colsS, valsS, mats);
      gemm_mfma_kernel<1, 32, FP0, 64><<<dim3(BB * NN / 32, 1), 256, 0, stream>>>(
          mats, WcTh[0], WcTl[0], bc[0], nullptr, gatesBuf, state, outT);
    }
    // ---- layer 1 ----
    {
      float* state = out_h + BNH;
      const float* xi = x01;
      float* outT = out_cur + (size_t)t * BNH;
      spmm1_l1_kernel<<<dim3(NN, 2), 256, 0, stream>>>(row_start, colsS, valsS, xi, state, mats);
      spmm2_kernel<1><<<dim3(NN, 2), 256, 0, stream>>>(row_start, colsS, valsS, mats);
      gemm_mfma_kernel<0, 32, FP1, 128><<<dim3(BB * NN / 32, 2), 256, 0, stream>>>(
          mats, WgTh[1], WgTl[1], bg[1], gatesBuf, nullptr, nullptr, nullptr);
      spmm1_state_kernel<1><<<dim3(NN / 2, 2), 256, 0, stream>>>(row_start, colsS, valsS, state,
                                                                 gatesBuf, mats);
      spmm2_state_kernel<1><<<dim3(NN / 2, 2), 256, 0, stream>>>(row_start, colsS, valsS, mats);
      gemm_mfma_kernel<1, 32, FP1, 64><<<dim3(BB * NN / 32, 1), 256, 0, stream>>>(
          mats, WcTh[1], WcTl[1], bc[1], nullptr, gatesBuf, state, outT);
    }
  }
}

// Round 13
// 1817.239 us; speedup vs baseline: 2.7657x; 1.0330x over previous
//
#include <hip/hip_runtime.h>
#include <hip/hip_bf16.h>
#include <math.h>

// Problem constants (fixed by the reference)
#define NN 1024
#define HH 64
#define TT 12
#define BB 8
#define INDIM 2
#define LL 2
#define NNZE 16384
#define MM 5

// Padded per-mat feature dims. Layer-0 order: [state(64), xi(2), pad(30)]; layer-1: [xi(64), state(64)]
#define FP0 96
#define FP1 128
#define CP0 (BB * FP0)   // 768
#define CP1 (BB * FP1)   // 1024

static constexpr size_t BNH = (size_t)BB * NN * HH;  // 524288

typedef short bf16x8 __attribute__((ext_vector_type(8)));
typedef float f32x4 __attribute__((ext_vector_type(4)));

// ---- bf16 helpers (functions, not macros — round-10 lesson) ----
__device__ __forceinline__ unsigned short f2bf(float x) {  // RNE
  unsigned u = __float_as_uint(x);
  u += 0x7FFFu + ((u >> 16) & 1u);
  return (unsigned short)(u >> 16);
}
__device__ __forceinline__ float bf2f(unsigned short h) {
  return __uint_as_float(((unsigned)h) << 16);
}
__device__ __forceinline__ void fma8_bf(float* acc, float v, uint4 pk) {
  const unsigned short* h = (const unsigned short*)&pk;
#pragma unroll
  for (int q = 0; q < 8; ++q) acc[q] += v * bf2f(h[q]);
}
__device__ __forceinline__ uint4 pack8(const float* a) {
  unsigned short h[8];
#pragma unroll
  for (int q = 0; q < 8; ++q) h[q] = f2bf(a[q]);
  return *(const uint4*)h;
}

// ---------------- small utility kernels ----------------
__global__ void zero_int_kernel(int* p, int n) {
  int i = blockIdx.x * blockDim.x + threadIdx.x;
  if (i < n) p[i] = 0;
}
__global__ void copy_kernel(const float* __restrict__ src, float* __restrict__ dst, int n) {
  int i = blockIdx.x * blockDim.x + threadIdx.x;
  if (i < n) dst[i] = src[i];
}
__global__ void cvt_kernel(const float* __restrict__ src, unsigned short* __restrict__ dst, int n) {
  int i = blockIdx.x * blockDim.x + threadIdx.x;
  if (i < n) dst[i] = f2bf(src[i]);
}

// ---------------- CSR build ----------------
__global__ void csr_count_kernel(const int* __restrict__ rows, int* __restrict__ counts) {
  int i = blockIdx.x * blockDim.x + threadIdx.x;
  if (i < 2 * NNZE) {
    int s = i / NNZE;
    atomicAdd(&counts[s * NN + rows[i]], 1);
  }
}
__global__ void csr_scan_kernel(const int* __restrict__ counts, int* __restrict__ row_start,
                                int* __restrict__ cursor) {
  __shared__ int bufA[NN];
  __shared__ int bufB[NN];
  int s = blockIdx.x;
  int t = threadIdx.x;
  bufA[t] = counts[s * NN + t];
  __syncthreads();
  int* src = bufA;
  int* dst = bufB;
  for (int off = 1; off < NN; off <<= 1) {
    dst[t] = src[t] + (t >= off ? src[t - off] : 0);
    __syncthreads();
    int* tmp = src; src = dst; dst = tmp;
  }
  row_start[s * (NN + 1) + t + 1] = src[t];
  cursor[s * NN + t] = (t == 0) ? 0 : src[t - 1];
  if (t == 0) row_start[s * (NN + 1)] = 0;
}
__global__ void csr_scatter_kernel(const int* __restrict__ rows, const int* __restrict__ colsIn,
                                   const float* __restrict__ valsIn, int* __restrict__ cursor,
                                   int* __restrict__ colsOut, float* __restrict__ valsOut) {
  int i = blockIdx.x * blockDim.x + threadIdx.x;
  if (i < 2 * NNZE) {
    int s = i / NNZE;
    int r = rows[i];
    int pos = atomicAdd(&cursor[s * NN + r], 1);
    colsOut[s * NNZE + pos] = colsIn[i];
    valsOut[s * NNZE + pos] = valsIn[i];
  }
}

// ---------------- weight permute + transpose + bf16 hi/lo split ----------------
__global__ void permwT_kernel(const float* __restrict__ W, unsigned short* __restrict__ WTh,
                              unsigned short* __restrict__ WTl, int F, int Fp, int J, int reord) {
  int Ktot = MM * Fp;
  int total = J * Ktot;
  for (int idx = blockIdx.x * blockDim.x + threadIdx.x; idx < total;
       idx += gridDim.x * blockDim.x) {
    int k = idx % Ktot;
    int j = idx / Ktot;
    int m = k / Fp;
    int fn = k - m * Fp;
    int fo;
    if (reord) {
      fo = (fn < HH) ? fn + INDIM : (fn < HH + INDIM ? fn - HH : -1);
    } else {
      fo = (fn < F) ? fn : -1;
    }
    float x = (fo >= 0) ? W[(size_t)(fo * MM + m) * J + j] : 0.f;
    unsigned u = __float_as_uint(x);
    WTh[idx] = (unsigned short)(u >> 16);
    float hf = __uint_as_float(u & 0xFFFF0000u);
    WTl[idx] = (unsigned short)(__float_as_uint(x - hf) >> 16);
  }
}

// ---------------- spmm1 layer1, gates pass ----------------
// Sources bf16 [B][N][64] (x01Bf, stateBf1). 8 cols/thread, 2 rows/block, grid (NN/2, 2).
__global__ __launch_bounds__(256) void spmm1_l1_kernel(
    const int* __restrict__ row_start, const int* __restrict__ cols,
    const float* __restrict__ vals, const unsigned short* __restrict__ xiB,
    const unsigned short* __restrict__ stateB, unsigned short* __restrict__ matsB) {
  const int tid = threadIdx.x;
  const int r = blockIdx.x * 2 + (tid >> 7);
  const int slot = tid & 127;
  const int s = blockIdx.y;
  const int b = slot >> 4;
  const int f8 = (slot & 15) * 8;
  const bool isX = (f8 < HH);
  const unsigned short* sb = (isX ? xiB : stateB) + (size_t)b * NN * HH + (isX ? f8 : f8 - HH);

  const int* rs = row_start + s * (NN + 1);
  const int* cs = cols + s * NNZE;
  const float* vs = vals + s * NNZE;
  const int start = rs[r], end = rs[r + 1];

  float a0[8] = {}, a1[8] = {}, a2[8] = {}, a3[8] = {};
  int e = start;
  for (; e + 3 < end; e += 4) {
    int c0 = cs[e], c1 = cs[e + 1], c2 = cs[e + 2], c3 = cs[e + 3];
    float v0 = vs[e], v1 = vs[e + 1], v2 = vs[e + 2], v3 = vs[e + 3];
    uint4 p0 = *(const uint4*)(sb + (size_t)c0 * HH);
    uint4 p1 = *(const uint4*)(sb + (size_t)c1 * HH);
    uint4 p2 = *(const uint4*)(sb + (size_t)c2 * HH);
    uint4 p3 = *(const uint4*)(sb + (size_t)c3 * HH);
    fma8_bf(a0, v0, p0); fma8_bf(a1, v1, p1); fma8_bf(a2, v2, p2); fma8_bf(a3, v3, p3);
  }
  for (; e < end; ++e) {
    uint4 p0 = *(const uint4*)(sb + (size_t)cs[e] * HH);
    fma8_bf(a0, vs[e], p0);
  }
  float o[8];
#pragma unroll
  for (int q = 0; q < 8; ++q) o[q] = (a0[q] + a1[q]) + (a2[q] + a3[q]);
  *(uint4*)(matsB + (size_t)(1 + 2 * s) * (NN * CP1) + (size_t)r * CP1 + slot * 8) = pack8(o);

  if (s == 0) {  // x0 row r: direct bf16 copy
    *(uint4*)(matsB + (size_t)r * CP1 + slot * 8) = *(const uint4*)(sb + (size_t)r * HH);
  }
}

// ---------------- spmm1 layer0, gates pass (state-first layout) ----------------
// 96 slots/row (12 per batch), 2 rows/block (128-thread halves, 96 active each), grid (NN/2, 2).
__global__ __launch_bounds__(256) void spmm1_l0_kernel(
    const int* __restrict__ row_start, const int* __restrict__ cols,
    const float* __restrict__ vals, const unsigned short* __restrict__ xiB,  // [B][N][2]
    const unsigned short* __restrict__ stateB,                                // [B][N][64]
    unsigned short* __restrict__ matsB) {
  const int tid = threadIdx.x;
  const int slot = tid & 127;
  constexpr int SLOTS_PB = FP0 / 8;  // 12
  if (slot >= 96) return;
  const int r = blockIdx.x * 2 + (tid >> 7);
  const int s = blockIdx.y;
  const int b = slot / SLOTS_PB;
  const int f8 = (slot - b * SLOTS_PB) * 8;
  const int c8 = b * FP0 + f8;

  unsigned short* x1p = matsB + (size_t)(1 + 2 * s) * (NN * CP0) + (size_t)r * CP0 + c8;
  unsigned short* x0p = matsB + (size_t)r * CP0 + c8;

  const int* rs = row_start + s * (NN + 1);
  const int* cs = cols + s * NNZE;
  const float* vs = vals + s * NNZE;
  const int start = rs[r], end = rs[r + 1];

  if (f8 < HH) {
    const unsigned short* sb = stateB + (size_t)b * NN * HH + f8;
    float a0[8] = {}, a1[8] = {}, a2[8] = {}, a3[8] = {};
    int e = start;
    for (; e + 3 < end; e += 4) {
      int c0 = cs[e], c1 = cs[e + 1], c2 = cs[e + 2], c3 = cs[e + 3];
      float v0 = vs[e], v1 = vs[e + 1], v2 = vs[e + 2], v3 = vs[e + 3];
      uint4 p0 = *(const uint4*)(sb + (size_t)c0 * HH);
      uint4 p1 = *(const uint4*)(sb + (size_t)c1 * HH);
      uint4 p2 = *(const uint4*)(sb + (size_t)c2 * HH);
      uint4 p3 = *(const uint4*)(sb + (size_t)c3 * HH);
      fma8_bf(a0, v0, p0); fma8_bf(a1, v1, p1); fma8_bf(a2, v2, p2); fma8_bf(a3, v3, p3);
    }
    for (; e < end; ++e) {
      uint4 p0 = *(const uint4*)(sb + (size_t)cs[e] * HH);
      fma8_bf(a0, vs[e], p0);
    }
    float o[8];
#pragma unroll
    for (int q = 0; q < 8; ++q) o[q] = (a0[q] + a1[q]) + (a2[q] + a3[q]);
    *(uint4*)x1p = pack8(o);
    if (s == 0) *(uint4*)x0p = *(const uint4*)(sb + (size_t)r * HH);
  } else if (f8 == HH) {
    const unsigned short* xb = xiB + (size_t)b * NN * INDIM;
    float p0 = 0.f, q0 = 0.f, p1 = 0.f, q1 = 0.f;
    int e = start;
    for (; e + 1 < end; e += 2) {
      unsigned w0 = *(const unsigned*)(xb + (size_t)cs[e] * INDIM);
      unsigned w1 = *(const unsigned*)(xb + (size_t)cs[e + 1] * INDIM);
      float v0 = vs[e], v1 = vs[e + 1];
      p0 += v0 * bf2f((unsigned short)(w0 & 0xFFFF));
      q0 += v0 * bf2f((unsigned short)(w0 >> 16));
      p1 += v1 * bf2f((unsigned short)(w1 & 0xFFFF));
      q1 += v1 * bf2f((unsigned short)(w1 >> 16));
    }
    if (e < end) {
      unsigned w0 = *(const unsigned*)(xb + (size_t)cs[e] * INDIM);
      float v0 = vs[e];
      p0 += v0 * bf2f((unsigned short)(w0 & 0xFFFF));
      q0 += v0 * bf2f((unsigned short)(w0 >> 16));
    }
    unsigned short h[8] = {f2bf(p0 + p1), f2bf(q0 + q1), 0, 0, 0, 0, 0, 0};
    *(uint4*)x1p = *(const uint4*)h;
    if (s == 0) {
      unsigned w = *(const unsigned*)(xb + (size_t)r * INDIM);
      unsigned short h0[8] = {(unsigned short)(w & 0xFFFF), (unsigned short)(w >> 16),
                              0, 0, 0, 0, 0, 0};
      *(uint4*)x0p = *(const uint4*)h0;
    }
  } else {
    uint4 z = {0, 0, 0, 0};
    *(uint4*)x1p = z;
    if (s == 0) *(uint4*)x0p = z;
  }
}

// ---------------- spmm1 candidate pass: state cols only (gathers rstateB bf16) ----------------
// 64 slots/row, 4 rows/block, grid (NN/4, 2).
template <int LAYER>
__global__ __launch_bounds__(256) void spmm1_state_kernel(
    const int* __restrict__ row_start, const int* __restrict__ cols,
    const float* __restrict__ vals, const unsigned short* __restrict__ rstateB,
    unsigned short* __restrict__ matsB) {
  constexpr int FPP = (LAYER == 0) ? FP0 : FP1;
  constexpr int CP = BB * FPP;
  constexpr int BASE = (LAYER == 0) ? 0 : HH;
  const int tid = threadIdx.x;
  const int r = blockIdx.x * 4 + (tid >> 6);
  const int slot = tid & 63;
  const int b = slot >> 3;
  const int f8 = (slot & 7) * 8;
  const int s = blockIdx.y;
  const unsigned short* rb = rstateB + (size_t)b * NN * HH + f8;

  const int* rs = row_start + s * (NN + 1);
  const int* cs = cols + s * NNZE;
  const float* vs = vals + s * NNZE;
  const int start = rs[r], end = rs[r + 1];

  float a0[8] = {}, a1[8] = {}, a2[8] = {}, a3[8] = {};
  int e = start;
  for (; e + 3 < end; e += 4) {
    int c0 = cs[e], c1 = cs[e + 1], c2 = cs[e + 2], c3 = cs[e + 3];
    float v0 = vs[e], v1 = vs[e + 1], v2 = vs[e + 2], v3 = vs[e + 3];
    uint4 p0 = *(const uint4*)(rb + (size_t)c0 * HH);
    uint4 p1 = *(const uint4*)(rb + (size_t)c1 * HH);
    uint4 p2 = *(const uint4*)(rb + (size_t)c2 * HH);
    uint4 p3 = *(const uint4*)(rb + (size_t)c3 * HH);
    fma8_bf(a0, v0, p0); fma8_bf(a1, v1, p1); fma8_bf(a2, v2, p2); fma8_bf(a3, v3, p3);
  }
  for (; e < end; ++e) {
    uint4 p0 = *(const uint4*)(rb + (size_t)cs[e] * HH);
    fma8_bf(a0, vs[e], p0);
  }
  float o[8];
#pragma unroll
  for (int q = 0; q < 8; ++q) o[q] = (a0[q] + a1[q]) + (a2[q] + a3[q]);
  const int c8 = b * FPP + BASE + f8;
  *(uint4*)(matsB + (size_t)(1 + 2 * s) * (NN * CP) + (size_t)r * CP + c8) = pack8(o);

  if (s == 0) {  // x0 state cols = rstate (already bf16)
    *(uint4*)(matsB + (size_t)r * CP + c8) = *(const uint4*)(rb + (size_t)r * HH);
  }
}

// ---------------- spmm2 gates pass: x2 = 2*A@x1 - x0 (bf16 in/out) ----------------
// L1: 128 slots/row; L0: 96 slots/row (pads flow through as zeros). 2 rows/block, grid (NN/2,2).
template <int LAYER>
__global__ __launch_bounds__(256) void spmm2_kernel(
    const int* __restrict__ row_start, const int* __restrict__ cols,
    const float* __restrict__ vals, unsigned short* __restrict__ matsB) {
  constexpr int FPP = (LAYER == 0) ? FP0 : FP1;
  constexpr int CP = BB * FPP;
  constexpr int SLOTS = CP / 8;  // 96 or 128
  const int tid = threadIdx.x;
  const int slot = tid & 127;
  if (slot >= SLOTS) return;
  const int r = blockIdx.x * 2 + (tid >> 7);
  const int s = blockIdx.y;
  const int c8 = slot * 8;
  const size_t NC = (size_t)NN * CP;
  const unsigned short* xin = matsB + (size_t)(1 + 2 * s) * NC + c8;

  const int* rs = row_start + s * (NN + 1);
  const int* cs = cols + s * NNZE;
  const float* vs = vals + s * NNZE;
  const int start = rs[r], end = rs[r + 1];

  float a0[8] = {}, a1[8] = {}, a2[8] = {}, a3[8] = {};
  int e = start;
  for (; e + 3 < end; e += 4) {
    int c0 = cs[e], c1 = cs[e + 1], c2 = cs[e + 2], c3 = cs[e + 3];
    float v0 = vs[e], v1 = vs[e + 1], v2 = vs[e + 2], v3 = vs[e + 3];
    uint4 p0 = *(const uint4*)(xin + (size_t)c0 * CP);
    uint4 p1 = *(const uint4*)(xin + (size_t)c1 * CP);
    uint4 p2 = *(const uint4*)(xin + (size_t)c2 * CP);
    uint4 p3 = *(const uint4*)(xin + (size_t)c3 * CP);
    fma8_bf(a0, v0, p0); fma8_bf(a1, v1, p1); fma8_bf(a2, v2, p2); fma8_bf(a3, v3, p3);
  }
  for (; e < end; ++e) {
    uint4 p0 = *(const uint4*)(xin + (size_t)cs[e] * CP);
    fma8_bf(a0, vs[e], p0);
  }
  uint4 x0v = *(const uint4*)(matsB + (size_t)r * CP + c8);
  const unsigned short* x0h = (const unsigned short*)&x0v;
  float o[8];
#pragma unroll
  for (int q = 0; q < 8; ++q)
    o[q] = 2.f * ((a0[q] + a1[q]) + (a2[q] + a3[q])) - bf2f(x0h[q]);
  *(uint4*)(matsB + (size_t)(2 + 2 * s) * NC + (size_t)r * CP + c8) = pack8(o);
}

// ---------------- spmm2 candidate pass: state cols only ----------------
template <int LAYER>
__global__ __launch_bounds__(256) void spmm2_state_kernel(
    const int* __restrict__ row_start, const int* __restrict__ cols,
    const float* __restrict__ vals, unsigned short* __restrict__ matsB) {
  constexpr int FPP = (LAYER == 0) ? FP0 : FP1;
  constexpr int CP = BB * FPP;
  constexpr int BASE = (LAYER == 0) ? 0 : HH;
  const int tid = threadIdx.x;
  const int r = blockIdx.x * 4 + (tid >> 6);
  const int slot = tid & 63;
  const int b = slot >> 3;
  const int f8 = (slot & 7) * 8;
  const int s = blockIdx.y;
  const int c8 = b * FPP + BASE + f8;
  const size_t NC = (size_t)NN * CP;
  const unsigned short* xin = matsB + (size_t)(1 + 2 * s) * NC + c8;

  const int* rs = row_start + s * (NN + 1);
  const int* cs = cols + s * NNZE;
  const float* vs = vals + s * NNZE;
  const int start = rs[r], end = rs[r + 1];

  float a0[8] = {}, a1[8] = {}, a2[8] = {}, a3[8] = {};
  int e = start;
  for (; e + 3 < end; e += 4) {
    int c0 = cs[e], c1 = cs[e + 1], c2 = cs[e + 2], c3 = cs[e + 3];
    float v0 = vs[e], v1 = vs[e + 1], v2 = vs[e + 2], v3 = vs[e + 3];
    uint4 p0 = *(const uint4*)(xin + (size_t)c0 * CP);
    uint4 p1 = *(const uint4*)(xin + (size_t)c1 * CP);
    uint4 p2 = *(const uint4*)(xin + (size_t)c2 * CP);
    uint4 p3 = *(const uint4*)(xin + (size_t)c3 * CP);
    fma8_bf(a0, v0, p0); fma8_bf(a1, v1, p1); fma8_bf(a2, v2, p2); fma8_bf(a3, v3, p3);
  }
  for (; e < end; ++e) {
    uint4 p0 = *(const uint4*)(xin + (size_t)cs[e] * CP);
    fma8_bf(a0, vs[e], p0);
  }
  uint4 x0v = *(const uint4*)(matsB + (size_t)r * CP + c8);
  const unsigned short* x0h = (const unsigned short*)&x0v;
  float o[8];
#pragma unroll
  for (int q = 0; q < 8; ++q)
    o[q] = 2.f * ((a0[q] + a1[q]) + (a2[q] + a3[q])) - bf2f(x0h[q]);
  *(uint4*)(matsB + (size_t)(2 + 2 * s) * NC + (size_t)r * CP + c8) = pack8(o);
}

// ---------------- MFMA GEMM: A = bf16 mats (single plane), W = bf16 hi+lo ----------------
// BM=32, 4 waves in 1x4 (each 32 rows x 16 cols). 4 MFMA/phase.
// MODE 0 (JJ=128): jj<64 -> rstateB = bf16(sigmoid(v)*state); jj>=64 -> uBuf = sigmoid(v)
// MODE 1 (JJ=64): c=tanh(v); u=uBuf; ns=u*s+(1-u)c -> state (fp32), stateBf, [outBf], [outT]
template <int MODE, int FPP, int JJ>
__global__ __launch_bounds__(256) void gemm_mfma_kernel(
    const unsigned short* __restrict__ matsB, const unsigned short* __restrict__ WTh,
    const unsigned short* __restrict__ WTl, const float* __restrict__ bias,
    unsigned short* __restrict__ rstateB, float* __restrict__ uBuf, float* __restrict__ state,
    unsigned short* __restrict__ stateBf, unsigned short* __restrict__ outBf,
    float* __restrict__ outT) {
  constexpr int BM = 32, KT = 32, LDR = 40;
  constexpr int CP = BB * FPP;
  constexpr int KTOT = MM * FPP;
  constexpr int NPH = KTOT / KT;

  __shared__ unsigned short As[2][BM][LDR];
  __shared__ unsigned short Ws[2][2][64][LDR];

  const int tid = threadIdx.x;
  const int lane = tid & 63;
  const int wid = tid >> 6;
  const int wc = wid * 16;
  const int lr = lane & 15, g = lane >> 4;

  const int bn0 = blockIdx.x * BM;
  const int jb0 = blockIdx.y * 64;
  const int nB = bn0 >> 10;
  const int n0 = bn0 & (NN - 1);

  const int arow = tid >> 2;          // A: tid<128 -> rows 0..31 ; W: rows 0..63
  const int acol = (tid & 3) * 8;
  const bool doA = (tid < 128);

  uint4 aval, wh, wl;

  auto gload = [&](int ph) {
    const int m = (ph * KT) / FPP;
    const int f0 = (ph * KT) - m * FPP;
    if (doA) {
      aval = *(const uint4*)(matsB + (size_t)m * NN * CP + (size_t)(n0 + arow) * CP +
                             nB * FPP + f0 + acol);
    }
    const size_t woff = (size_t)(jb0 + arow) * KTOT + ph * KT + acol;
    wh = *(const uint4*)(WTh + woff);
    wl = *(const uint4*)(WTl + woff);
  };
  auto stos = [&](int buf) {
    if (doA) *(uint4*)&As[buf][arow][acol] = aval;
    *(uint4*)&Ws[buf][0][arow][acol] = wh;
    *(uint4*)&Ws[buf][1][arow][acol] = wl;
  };

  f32x4 acc[2] = {};

  auto domfma = [&](int cur) {
    bf16x8 a0 = *(const bf16x8*)&As[cur][0 * 16 + lr][g * 8];
    bf16x8 a1 = *(const bf16x8*)&As[cur][1 * 16 + lr][g * 8];
    bf16x8 bh = *(const bf16x8*)&Ws[cur][0][wc + lr][g * 8];
    bf16x8 bl = *(const bf16x8*)&Ws[cur][1][wc + lr][g * 8];
    acc[0] = __builtin_amdgcn_mfma_f32_16x16x32_bf16(a0, bh, acc[0], 0, 0, 0);
    acc[0] = __builtin_amdgcn_mfma_f32_16x16x32_bf16(a0, bl, acc[0], 0, 0, 0);
    acc[1] = __builtin_amdgcn_mfma_f32_16x16x32_bf16(a1, bh, acc[1], 0, 0, 0);
    acc[1] = __builtin_amdgcn_mfma_f32_16x16x32_bf16(a1, bl, acc[1], 0, 0, 0);
  };

  gload(0);
  stos(0);
  __syncthreads();

  for (int ph = 0; ph < NPH; ++ph) {
    const int cur = ph & 1;
    if (ph + 1 < NPH) gload(ph + 1);
    domfma(cur);
    if (ph + 1 < NPH) {
      stos(cur ^ 1);
      __syncthreads();
    }
  }

  // epilogue: C/D frag mapping col = lane&15, row = (lane>>4)*4 + reg
  const int jj = jb0 + wc + lr;
  const float bs = bias[jj];
#pragma unroll
  for (int tr = 0; tr < 2; ++tr) {
#pragma unroll
    for (int q = 0; q < 4; ++q) {
      const int bn = bn0 + tr * 16 + g * 4 + q;
      const int n = bn & (NN - 1);
      const int b = bn >> 10;
      float v = acc[tr][q] + bs;
      if (MODE == 0) {
        float sg = 1.f / (1.f + expf(-v));
        if (jj < HH) {
          size_t si = (size_t)b * (NN * HH) + (size_t)n * HH + jj;
          rstateB[si] = f2bf(sg * state[si]);
        } else {
          uBuf[(size_t)bn * HH + (jj - HH)] = sg;
        }
      } else {
        float c = tanhf(v);
        float u = uBuf[(size_t)bn * HH + jj];
        size_t si = (size_t)b * (NN * HH) + (size_t)n * HH + jj;
        float s = state[si];
        float ns = u * s + (1.f - u) * c;
        state[si] = ns;
        stateBf[si] = f2bf(ns);
        if (outBf) outBf[si] = f2bf(ns);
        if (outT) outT[si] = ns;
      }
    }
  }
}

// ---------------- host orchestration ----------------
extern "C" void kernel_launch(void* const* d_in, const int* in_sizes, int n_in, void* d_out,
                              int out_size, void* d_ws, size_t ws_size, hipStream_t stream) {
  const float* inputs = (const float*)d_in[0];
  const float* init_h = (const float*)d_in[1];
  const int* sup_rows = (const int*)d_in[2];
  const int* sup_cols = (const int*)d_in[3];
  const float* sup_vals = (const float*)d_in[4];
  const float* Wg[2] = {(const float*)d_in[5], (const float*)d_in[9]};
  const float* bg[2] = {(const float*)d_in[6], (const float*)d_in[10]};
  const float* Wc[2] = {(const float*)d_in[7], (const float*)d_in[11]};
  const float* bc[2] = {(const float*)d_in[8], (const float*)d_in[12]};

  float* out_h = (float*)d_out;                  // [L][B*N*H] final hidden states
  float* out_cur = out_h + (size_t)LL * BNH;     // [T][B*N*H] layer-1 outputs

  char* p = (char*)d_ws;
  auto alloc = [&](size_t bytes) -> void* {
    void* r = (void*)p;
    p += (bytes + 255) & ~(size_t)255;
    return r;
  };
  int* colsS = (int*)alloc(2 * NNZE * sizeof(int));
  float* valsS = (float*)alloc(2 * NNZE * sizeof(float));
  int* row_start = (int*)alloc(2 * (NN + 1) * sizeof(int));
  int* cursor = (int*)alloc(2 * NN * sizeof(int));
  int* counts = (int*)alloc(2 * NN * sizeof(int));
  const int K0 = MM * FP0, K1 = MM * FP1;  // 480, 640
  unsigned short* WgTh[2]; unsigned short* WgTl[2];
  unsigned short* WcTh[2]; unsigned short* WcTl[2];
  WgTh[0] = (unsigned short*)alloc((size_t)128 * K0 * 2);
  WgTl[0] = (unsigned short*)alloc((size_t)128 * K0 * 2);
  WcTh[0] = (unsigned short*)alloc((size_t)64 * K0 * 2);
  WcTl[0] = (unsigned short*)alloc((size_t)64 * K0 * 2);
  WgTh[1] = (unsigned short*)alloc((size_t)128 * K1 * 2);
  WgTl[1] = (unsigned short*)alloc((size_t)128 * K1 * 2);
  WcTh[1] = (unsigned short*)alloc((size_t)64 * K1 * 2);
  WcTl[1] = (unsigned short*)alloc((size_t)64 * K1 * 2);
  unsigned short* matsB = (unsigned short*)alloc((size_t)MM * NN * CP1 * 2);   // 10.5 MB
  unsigned short* stateBf = (unsigned short*)alloc(2 * BNH * 2);               // both layers
  unsigned short* x01Bf = (unsigned short*)alloc(BNH * 2);
  unsigned short* rstateB = (unsigned short*)alloc(BNH * 2);
  float* uBuf = (float*)alloc(BNH * sizeof(float));
  unsigned short* inputsBf = (unsigned short*)alloc((size_t)TT * BB * NN * INDIM * 2);
  unsigned short* stateBf0 = stateBf;
  unsigned short* stateBf1 = stateBf + BNH;

  // --- CSR build ---
  zero_int_kernel<<<(2 * NN + 255) / 256, 256, 0, stream>>>(counts, 2 * NN);
  csr_count_kernel<<<(2 * NNZE + 255) / 256, 256, 0, stream>>>(sup_rows, counts);
  csr_scan_kernel<<<2, NN, 0, stream>>>(counts, row_start, cursor);
  csr_scatter_kernel<<<(2 * NNZE + 255) / 256, 256, 0, stream>>>(sup_rows, sup_cols, sup_vals,
                                                                 cursor, colsS, valsS);
  // --- weights (hi/lo transposed planes) ---
  permwT_kernel<<<(128 * K0 + 255) / 256, 256, 0, stream>>>(Wg[0], WgTh[0], WgTl[0], 66, FP0, 128, 1);
  permwT_kernel<<<(64 * K0 + 255) / 256, 256, 0, stream>>>(Wc[0], WcTh[0], WcTl[0], 66, FP0, 64, 1);
  permwT_kernel<<<(128 * K1 + 255) / 256, 256, 0, stream>>>(Wg[1], WgTh[1], WgTl[1], 128, FP1, 128, 0);
  permwT_kernel<<<(64 * K1 + 255) / 256, 256, 0, stream>>>(Wc[1], WcTh[1], WcTl[1], 128, FP1, 64, 0);
  // --- init states + bf16 copies + bf16 inputs ---
  copy_kernel<<<((int)(LL * BNH) + 255) / 256, 256, 0, stream>>>(init_h, out_h, (int)(LL * BNH));
  cvt_kernel<<<((int)(2 * BNH) + 255) / 256, 256, 0, stream>>>(init_h, stateBf, (int)(2 * BNH));
  cvt_kernel<<<(TT * BB * NN * INDIM + 255) / 256, 256, 0, stream>>>(
      inputs, inputsBf, TT * BB * NN * INDIM);

  for (int t = 0; t < TT; ++t) {
    // ---- layer 0 ----
    {
      float* state = out_h;
      const unsigned short* xiB = inputsBf + (size_t)t * BB * NN * INDIM;
      spmm1_l0_kernel<<<dim3(NN / 2, 2), 256, 0, stream>>>(row_start, colsS, valsS, xiB,
                                                           stateBf0, matsB);
      spmm2_kernel<0><<<dim3(NN / 2, 2), 256, 0, stream>>>(row_start, colsS, valsS, matsB);
      gemm_mfma_kernel<0, FP0, 128><<<dim3(BB * NN / 32, 2), 256, 0, stream>>>(
          matsB, WgTh[0], WgTl[0], bg[0], rstateB, uBuf, state, nullptr, nullptr, nullptr);
      spmm1_state_kernel<0><<<dim3(NN / 4, 2), 256, 0, stream>>>(row_start, colsS, valsS,
                                                                 rstateB, matsB);
      spmm2_state_kernel<0><<<dim3(NN / 4, 2), 256, 0, stream>>>(row_start, colsS, valsS, matsB);
      gemm_mfma_kernel<1, FP0, 64><<<dim3(BB * NN / 32, 1), 256, 0, stream>>>(
          matsB, WcTh[0], WcTl[0], bc[0], nullptr, uBuf, state, stateBf0, x01Bf, nullptr);
    }
    // ---- layer 1 ----
    {
      float* state = out_h + BNH;
      float* outT = out_cur + (size_t)t * BNH;
      spmm1_l1_kernel<<<dim3(NN / 2, 2), 256, 0, stream>>>(row_start, colsS, valsS, x01Bf,
                                                           stateBf1, matsB);
      spmm2_kernel<1><<<dim3(NN / 2, 2), 256, 0, stream>>>(row_start, colsS, valsS, matsB);
      gemm_mfma_kernel<0, FP1, 128><<<dim3(BB * NN / 32, 2), 256, 0, stream>>>(
          matsB, WgTh[1], WgTl[1], bg[1], rstateB, uBuf, state, nullptr, nullptr, nullptr);
      spmm1_state_kernel<1><<<dim3(NN / 4, 2), 256, 0, stream>>>(row_start, colsS, valsS,
                                                                 rstateB, matsB);
      spmm2_state_kernel<1><<<dim3(NN / 4, 2), 256, 0, stream>>>(row_start, colsS, valsS, matsB);
      gemm_mfma_kernel<1, FP1, 64><<<dim3(BB * NN / 32, 1), 256, 0, stream>>>(
          matsB, WcTh[1], WcTl[1], bc[1], nullptr, uBuf, state, stateBf1, nullptr, outT);
    }
  }
}